// Round 1
// baseline (567.281 us; speedup 1.0000x reference)
//
#include <hip/hip_runtime.h>
#include <math.h>

#define DIMC 64
#define DIN  128
#define LSEQ 9216
#define NPB  (DIMC*LSEQ)      // 589824 elements per batch
#define NCH  36               // scan chunks
#define CTL  256              // chunk length: NCH*CTL == LSEQ

__device__ __forceinline__ float siluf(float v)    { return v / (1.f + __expf(-v)); }
__device__ __forceinline__ float softplusf(float v){ return (v > 20.f) ? v : log1pf(__expf(v)); }
__device__ __forceinline__ float clip10(float v)   { return fminf(10.f, fmaxf(-10.f, v)); }

// ---------------- K1: per-batch sum / sumsq ----------------
__global__ void k_reduce(const float* __restrict__ x, float* __restrict__ sums) {
  int b = blockIdx.y;
  const float* xb = x + (size_t)b * NPB;
  float s = 0.f, s2 = 0.f;
  for (int i = blockIdx.x * blockDim.x + threadIdx.x; i < NPB; i += gridDim.x * blockDim.x) {
    float v = xb[i]; s += v; s2 = fmaf(v, v, s2);
  }
  __shared__ float l1[256], l2[256];
  int t = threadIdx.x;
  l1[t] = s; l2[t] = s2; __syncthreads();
  for (int off = 128; off > 0; off >>= 1) {
    if (t < off) { l1[t] += l1[t + off]; l2[t] += l2[t + off]; }
    __syncthreads();
  }
  if (t == 0) { atomicAdd(&sums[2*b], l1[0]); atomicAdd(&sums[2*b+1], l2[0]); }
}

// ---------------- K2: normalize + clip; write res (B,C,L) and seq (B,L,C) ----------------
__global__ void k_norm(const float* __restrict__ x, const float* __restrict__ gam,
                       const float* __restrict__ bet, const float* __restrict__ sums,
                       float* __restrict__ seq, float* __restrict__ res) {
  int b = blockIdx.y, l0 = blockIdx.x * 64;
  float mean = sums[2*b] * (1.f / NPB);
  float var  = sums[2*b+1] * (1.f / NPB) - mean * mean;
  float inv  = rsqrtf(var + 1e-5f);
  __shared__ float tile[64][65];
  int t = threadIdx.x;
  int lr = t & 63, cg = t >> 6;
  #pragma unroll
  for (int i = 0; i < 16; i++) {
    int c = i * 4 + cg;
    size_t idx = ((size_t)(b * DIMC + c)) * LSEQ + l0 + lr;
    float v = x[idx];
    v = (v - mean) * inv * gam[c] + bet[c];
    v = clip10(v);
    res[idx] = v;
    tile[c][lr] = v;
  }
  __syncthreads();
  int cc = t & 63, lg = t >> 6;
  #pragma unroll
  for (int i = 0; i < 16; i++) {
    int l = i * 4 + lg;
    seq[((size_t)(b * LSEQ + l0 + l)) * DIMC + cc] = tile[cc][l];
  }
}

// ---------------- K2p: prep — transpose W_in; fold proj_w@W_out ----------------
__global__ void k_prep(const float* __restrict__ W_in, const float* __restrict__ proj_w,
                       const float* __restrict__ W_out, const float* __restrict__ b_out,
                       const float* __restrict__ proj_b,
                       float* __restrict__ Wt, float* __restrict__ Mt, float* __restrict__ bp) {
  int t = threadIdx.x;
  for (int i = t; i < 256 * 64; i += 256) {       // Wt[k*256+c] = W_in[c*64+k]
    int k = i >> 8, c = i & 255;
    Wt[i] = W_in[c * 64 + k];
  }
  for (int i = t; i < 128 * 64; i += 256) {       // Mt[d*64+o] = sum_c proj_w[o,c]*W_out[c,d]
    int d = i >> 6, o = i & 63;
    float a = 0.f;
    for (int c = 0; c < 64; c++) a = fmaf(proj_w[o * 64 + c], W_out[c * DIN + d], a);
    Mt[i] = a;
  }
  if (t < 64) {
    float a = proj_b[t];
    for (int c = 0; c < 64; c++) a = fmaf(proj_w[t * 64 + c], b_out[c], a);
    bp[t] = a;
  }
}

// ---------------- K3: in-proj GEMM: xz = seq @ W_in^T + b_in ----------------
__global__ void k_inproj(const float* __restrict__ seq, const float* __restrict__ Wt,
                         const float* __restrict__ b_in,
                         float* __restrict__ xo, float* __restrict__ zo) {
  int row0 = blockIdx.x * 16;
  int c = threadIdx.x;                       // 0..255 output column
  float acc[16];
  float bi = b_in[c];
  #pragma unroll
  for (int r = 0; r < 16; r++) acc[r] = bi;
  const float* sp = seq + (size_t)row0 * DIMC;
  #pragma unroll 4
  for (int k = 0; k < 64; k++) {
    float w = Wt[k * 256 + c];
    #pragma unroll
    for (int r = 0; r < 16; r++) acc[r] = fmaf(w, sp[r * 64 + k], acc[r]);
  }
  #pragma unroll
  for (int r = 0; r < 16; r++) {
    size_t rr = (size_t)(row0 + r);
    if (c < DIN) xo[rr * DIN + c] = acc[r];
    else         zo[rr * DIN + (c - DIN)] = acc[r];
  }
}

// ---------------- K4: depthwise conv+SiLU, x-proj(36), dt(128) ----------------
__global__ void k_conv_proj(const float* __restrict__ x, const float* __restrict__ conv_w,
                            const float* __restrict__ conv_b, const float* __restrict__ W_xproj,
                            const float* __restrict__ W_dt, const float* __restrict__ b_dt,
                            float* __restrict__ xs, float* __restrict__ dt,
                            float* __restrict__ Bm, float* __restrict__ Cm) {
  int b = blockIdx.y, l0 = blockIdx.x * 64;
  __shared__ float xt[(64 + 3) * DIN];     // [l+3][d], row 0 == l0-3
  __shared__ float xst[64 * DIN];
  __shared__ float dt4[64 * 4];
  int t = threadIdx.x;
  for (int i = t; i < 67 * DIN; i += 256) {
    int lr = i / DIN, d = i % DIN;
    int l = l0 - 3 + lr;
    xt[i] = (l >= 0) ? x[((size_t)b * LSEQ + l) * DIN + d] : 0.f;
  }
  __syncthreads();
  for (int i = t; i < 64 * DIN; i += 256) {
    int lr = i / DIN, d = i % DIN;
    const float* cw = conv_w + d * 4;
    float v = conv_b[d];
    v = fmaf(xt[(lr + 0) * DIN + d], cw[0], v);
    v = fmaf(xt[(lr + 1) * DIN + d], cw[1], v);
    v = fmaf(xt[(lr + 2) * DIN + d], cw[2], v);
    v = fmaf(xt[(lr + 3) * DIN + d], cw[3], v);
    v = siluf(v);
    xst[i] = v;
    xs[((size_t)b * LSEQ + l0 + lr) * DIN + d] = v;
  }
  __syncthreads();
  for (int task = t; task < 64 * 36; task += 256) {
    int lr = task / 36, j = task % 36;
    const float* wr = W_xproj + j * DIN;
    const float* xr = xst + lr * DIN;
    float a = 0.f;
    #pragma unroll 4
    for (int d = 0; d < DIN; d++) a = fmaf(xr[d], wr[d], a);
    size_t row = (size_t)b * LSEQ + l0 + lr;
    if (j < 4)       dt4[lr * 4 + j] = a;
    else if (j < 20) Bm[row * 16 + (j - 4)] = a;
    else             Cm[row * 16 + (j - 20)] = a;
  }
  __syncthreads();
  for (int i = t; i < 64 * DIN; i += 256) {
    int lr = i / DIN, d = i % DIN;
    float a = b_dt[d];
    const float* wd = W_dt + d * 4;
    const float* dr = dt4 + lr * 4;
    a = fmaf(dr[0], wd[0], a);
    a = fmaf(dr[1], wd[1], a);
    a = fmaf(dr[2], wd[2], a);
    a = fmaf(dr[3], wd[3], a);
    dt[((size_t)b * LSEQ + l0 + lr) * DIN + d] = softplusf(a);
  }
}

// ---------------- K5a: scan chunk aggregates ----------------
__global__ void k_scanA(const float* __restrict__ dt, const float* __restrict__ Bmat,
                        const float* __restrict__ xs, const float* __restrict__ A_log,
                        float* __restrict__ Ap, float* __restrict__ Bg) {
  int g = blockIdx.x * 256 + threadIdx.x;
  int s = g & 15;
  int rest = g >> 4;
  int chunk = rest % NCH;
  int bd = rest / NCH;                  // b*128 + d
  int d = bd & 127, b = bd >> 7;
  float a = -__expf(A_log[d * 16 + s]);
  size_t base = (size_t)b * LSEQ + chunk * CTL;
  float h = 0.f, ap = 1.f;
  for (int i = 0; i < CTL; i++) {
    float dtv = dt[(base + i) * DIN + d];
    float bv  = Bmat[(base + i) * 16 + s];
    float xv  = xs[(base + i) * DIN + d];
    float dA  = __expf(dtv * a);
    h  = fmaf(dA, h, dtv * bv * xv);
    ap *= dA;
  }
  int chain = (bd * 16 + s) * NCH + chunk;
  Ap[chain] = ap;
  Bg[chain] = h;
}

// ---------------- K5b: sequential combine across chunks ----------------
__global__ void k_scanB(const float* __restrict__ Ap, const float* __restrict__ Bg,
                        float* __restrict__ hinit) {
  int chain = blockIdx.x * 256 + threadIdx.x;   // 0..4095
  if (chain >= 4096) return;
  const float* ap = Ap + (size_t)chain * NCH;
  const float* bg = Bg + (size_t)chain * NCH;
  float* hi = hinit + (size_t)chain * NCH;
  float h = 0.f;
  for (int c = 0; c < NCH; c++) {
    hi[c] = h;
    h = fmaf(ap[c], h, bg[c]);
  }
}

// ---------------- K5c: re-scan with init, reduce over s, gate ----------------
__global__ void k_scanC(const float* __restrict__ dt, const float* __restrict__ Bmat,
                        const float* __restrict__ Cmat, const float* __restrict__ xs,
                        const float* __restrict__ z, const float* __restrict__ A_log,
                        const float* __restrict__ Dp, const float* __restrict__ hinit,
                        float* __restrict__ y) {
  int g = blockIdx.x * 256 + threadIdx.x;
  int s = g & 15;
  int rest = g >> 4;
  int chunk = rest % NCH;
  int bd = rest / NCH;
  int d = bd & 127, b = bd >> 7;
  float a = -__expf(A_log[d * 16 + s]);
  float dp = Dp[d];
  size_t base = (size_t)b * LSEQ + chunk * CTL;
  float h = hinit[(size_t)(bd * 16 + s) * NCH + chunk];
  for (int i = 0; i < CTL; i++) {
    float dtv = dt[(base + i) * DIN + d];
    float bv  = Bmat[(base + i) * 16 + s];
    float xv  = xs[(base + i) * DIN + d];
    float cv  = Cmat[(base + i) * 16 + s];
    float dA  = __expf(dtv * a);
    h = fmaf(dA, h, dtv * bv * xv);
    float p = h * cv;
    p += __shfl_xor(p, 1);
    p += __shfl_xor(p, 2);
    p += __shfl_xor(p, 4);
    p += __shfl_xor(p, 8);
    if (s == 0) {
      float zv = z[(base + i) * DIN + d];
      y[(base + i) * DIN + d] = (p + xv * dp) * siluf(zv);
    }
  }
}

// ---------------- K6: out-proj + BN + GELU + residual + clip ----------------
__global__ void k_out(const float* __restrict__ y, const float* __restrict__ Mt,
                      const float* __restrict__ bp, const float* __restrict__ bn_g,
                      const float* __restrict__ bn_bt, const float* __restrict__ bn_m,
                      const float* __restrict__ bn_v, const float* __restrict__ res,
                      float* __restrict__ out) {
  int b = blockIdx.y, l0 = blockIdx.x * 64;
  int t = threadIdx.x;
  int c = t & 63, lg = t >> 6;
  __shared__ float tile[64][65];
  float acc[16];
  float bpc = bp[c];
  #pragma unroll
  for (int i = 0; i < 16; i++) acc[i] = bpc;
  const float* yb = y + ((size_t)b * LSEQ + l0 + lg * 16) * DIN;
  #pragma unroll 4
  for (int d = 0; d < DIN; d++) {
    float m = Mt[d * 64 + c];
    #pragma unroll
    for (int i = 0; i < 16; i++) acc[i] = fmaf(m, yb[i * DIN + d], acc[i]);
  }
  float g = bn_g[c], bt = bn_bt[c], mu = bn_m[c];
  float iv = rsqrtf(bn_v[c] + 1e-5f);
  #pragma unroll
  for (int i = 0; i < 16; i++) {
    float a = (acc[i] - mu) * iv * g + bt;
    a = 0.5f * a * (1.f + erff(a * 0.70710678118654752f));   // exact GELU
    tile[c][lg * 16 + i] = a;
  }
  __syncthreads();
  int l = t & 63, cg = t >> 6;
  #pragma unroll
  for (int i = 0; i < 16; i++) {
    int cc = cg * 16 + i;
    size_t idx = ((size_t)(b * DIMC + cc)) * LSEQ + l0 + l;
    out[idx] = clip10(res[idx] + tile[cc][l]);
  }
}

extern "C" void kernel_launch(void* const* d_in, const int* in_sizes, int n_in,
                              void* d_out, int out_size, void* d_ws, size_t ws_size,
                              hipStream_t stream) {
  const float* x       = (const float*)d_in[0];
  const float* gn_g    = (const float*)d_in[1];
  const float* gn_b    = (const float*)d_in[2];
  const float* W_in    = (const float*)d_in[3];
  const float* b_in    = (const float*)d_in[4];
  const float* conv_w  = (const float*)d_in[5];
  const float* conv_b  = (const float*)d_in[6];
  const float* W_xproj = (const float*)d_in[7];
  const float* W_dt    = (const float*)d_in[8];
  const float* b_dt    = (const float*)d_in[9];
  const float* A_log   = (const float*)d_in[10];
  const float* Dp      = (const float*)d_in[11];
  const float* W_out   = (const float*)d_in[12];
  const float* b_out   = (const float*)d_in[13];
  const float* proj_w  = (const float*)d_in[14];
  const float* proj_b  = (const float*)d_in[15];
  const float* bn_g    = (const float*)d_in[16];
  const float* bn_bt   = (const float*)d_in[17];
  const float* bn_m    = (const float*)d_in[18];
  const float* bn_v    = (const float*)d_in[19];

  float* ws = (float*)d_ws;
  float* sums = ws;                               // 4 used
  float* seq  = ws + 64;                          // 1179648  (B,L,C)
  float* res  = seq + 1179648;                    // 1179648  (B,C,L)
  float* xbuf = res + 1179648;                    // 2359296  (B,L,128) -> reused as y
  float* zbuf = xbuf + 2359296;                   // 2359296
  float* xsb  = zbuf + 2359296;                   // 2359296
  float* dtb  = xsb + 2359296;                    // 2359296
  float* Bmb  = dtb + 2359296;                    // 294912
  float* Cmb  = Bmb + 294912;                     // 294912
  float* Wt   = Cmb + 294912;                     // 16384
  float* Mt   = Wt + 16384;                       // 8192
  float* bp   = Mt + 8192;                        // 64
  float* Apb  = bp + 64;                          // 147456
  float* Bgb  = Apb + 147456;                     // 147456
  float* hib  = Bgb + 147456;                     // 147456
  float* ybuf = xbuf;                             // reuse: x consumed by k_conv_proj

  hipMemsetAsync(sums, 0, 64 * sizeof(float), stream);

  k_reduce<<<dim3(256, 2), 256, 0, stream>>>(x, sums);
  k_prep<<<1, 256, 0, stream>>>(W_in, proj_w, W_out, b_out, proj_b, Wt, Mt, bp);
  k_norm<<<dim3(144, 2), 256, 0, stream>>>(x, gn_g, gn_b, sums, seq, res);
  k_inproj<<<1152, 256, 0, stream>>>(seq, Wt, b_in, xbuf, zbuf);
  k_conv_proj<<<dim3(144, 2), 256, 0, stream>>>(xbuf, conv_w, conv_b, W_xproj, W_dt, b_dt,
                                                xsb, dtb, Bmb, Cmb);
  k_scanA<<<576, 256, 0, stream>>>(dtb, Bmb, xsb, A_log, Apb, Bgb);
  k_scanB<<<16, 256, 0, stream>>>(Apb, Bgb, hib);
  k_scanC<<<576, 256, 0, stream>>>(dtb, Bmb, Cmb, xsb, zbuf, A_log, Dp, hib, ybuf);
  k_out<<<dim3(144, 2), 256, 0, stream>>>(ybuf, Mt, bp, bn_g, bn_bt, bn_m, bn_v, res,
                                          (float*)d_out);
}

// Round 2
// 357.162 us; speedup vs baseline: 1.5883x; 1.5883x over previous
//
#include <hip/hip_runtime.h>
#include <math.h>

#define DIMC 64
#define DIN  128
#define LSEQ 9216
#define NPB  (DIMC*LSEQ)      // 589824 elements per batch
#define NCH  128              // scan chunks
#define CTL  72               // chunk length: NCH*CTL == LSEQ
#define NCHAIN 4096           // 2 batches * 128 d * 16 s

__device__ __forceinline__ float siluf(float v)    { return v / (1.f + __expf(-v)); }
__device__ __forceinline__ float softplusf(float v){ return (v > 20.f) ? v : log1pf(__expf(v)); }
__device__ __forceinline__ float clip10(float v)   { return fminf(10.f, fmaxf(-10.f, v)); }

// ---------------- K1: per-batch sum / sumsq ----------------
__global__ void k_reduce(const float* __restrict__ x, float* __restrict__ sums) {
  int b = blockIdx.y;
  const float* xb = x + (size_t)b * NPB;
  float s = 0.f, s2 = 0.f;
  for (int i = blockIdx.x * blockDim.x + threadIdx.x; i < NPB; i += gridDim.x * blockDim.x) {
    float v = xb[i]; s += v; s2 = fmaf(v, v, s2);
  }
  __shared__ float l1[256], l2[256];
  int t = threadIdx.x;
  l1[t] = s; l2[t] = s2; __syncthreads();
  for (int off = 128; off > 0; off >>= 1) {
    if (t < off) { l1[t] += l1[t + off]; l2[t] += l2[t + off]; }
    __syncthreads();
  }
  if (t == 0) { atomicAdd(&sums[2*b], l1[0]); atomicAdd(&sums[2*b+1], l2[0]); }
}

// ---------------- K2: normalize + clip; write res (B,C,L) and seq (B,L,C) ----------------
__global__ void k_norm(const float* __restrict__ x, const float* __restrict__ gam,
                       const float* __restrict__ bet, const float* __restrict__ sums,
                       float* __restrict__ seq, float* __restrict__ res) {
  int b = blockIdx.y, l0 = blockIdx.x * 64;
  float mean = sums[2*b] * (1.f / NPB);
  float var  = sums[2*b+1] * (1.f / NPB) - mean * mean;
  float inv  = rsqrtf(var + 1e-5f);
  __shared__ float tile[64][65];
  int t = threadIdx.x;
  int lr = t & 63, cg = t >> 6;
  #pragma unroll
  for (int i = 0; i < 16; i++) {
    int c = i * 4 + cg;
    size_t idx = ((size_t)(b * DIMC + c)) * LSEQ + l0 + lr;
    float v = x[idx];
    v = (v - mean) * inv * gam[c] + bet[c];
    v = clip10(v);
    res[idx] = v;
    tile[c][lr] = v;
  }
  __syncthreads();
  int cc = t & 63, lg = t >> 6;
  #pragma unroll
  for (int i = 0; i < 16; i++) {
    int l = i * 4 + lg;
    seq[((size_t)(b * LSEQ + l0 + l)) * DIMC + cc] = tile[cc][l];
  }
}

// ---------------- K2p: prep — transpose W_in; fold proj_w@W_out ----------------
__global__ void k_prep(const float* __restrict__ W_in, const float* __restrict__ proj_w,
                       const float* __restrict__ W_out, const float* __restrict__ b_out,
                       const float* __restrict__ proj_b,
                       float* __restrict__ Wt, float* __restrict__ Mt, float* __restrict__ bp) {
  int i = blockIdx.x * 256 + threadIdx.x;
  if (i < 16384) {                              // Wt[k*256+c] = W_in[c*64+k]
    int k = i >> 8, c = i & 255;
    Wt[i] = W_in[c * 64 + k];
    return;
  }
  int j = i - 16384;
  if (j < 8192) {                               // Mt[d*64+o] = sum_c proj_w[o,c]*W_out[c,d]
    int d = j >> 6, o = j & 63;
    float a = 0.f;
    for (int c = 0; c < 64; c++) a = fmaf(proj_w[o * 64 + c], W_out[c * DIN + d], a);
    Mt[j] = a;
    return;
  }
  int k2 = i - 24576;
  if (k2 < 64) {
    float a = proj_b[k2];
    for (int c = 0; c < 64; c++) a = fmaf(proj_w[k2 * 64 + c], b_out[c], a);
    bp[k2] = a;
  }
}

// ---------------- K3: in-proj GEMM: xz = seq @ W_in^T + b_in ----------------
__global__ void k_inproj(const float* __restrict__ seq, const float* __restrict__ Wt,
                         const float* __restrict__ b_in,
                         float* __restrict__ xo, float* __restrict__ zo) {
  int row0 = blockIdx.x * 16;
  int c = threadIdx.x;                       // 0..255 output column
  float acc[16];
  float bi = b_in[c];
  #pragma unroll
  for (int r = 0; r < 16; r++) acc[r] = bi;
  const float* sp = seq + (size_t)row0 * DIMC;
  #pragma unroll 4
  for (int k = 0; k < 64; k++) {
    float w = Wt[k * 256 + c];
    #pragma unroll
    for (int r = 0; r < 16; r++) acc[r] = fmaf(w, sp[r * 64 + k], acc[r]);
  }
  #pragma unroll
  for (int r = 0; r < 16; r++) {
    size_t rr = (size_t)(row0 + r);
    if (c < DIN) xo[rr * DIN + c] = acc[r];
    else         zo[rr * DIN + (c - DIN)] = acc[r];
  }
}

// ---------------- K4: depthwise conv+SiLU, x-proj(36), dt(128) ----------------
__global__ void k_conv_proj(const float* __restrict__ x, const float* __restrict__ conv_w,
                            const float* __restrict__ conv_b, const float* __restrict__ W_xproj,
                            const float* __restrict__ W_dt, const float* __restrict__ b_dt,
                            float* __restrict__ xs, float* __restrict__ dt,
                            float* __restrict__ Bm, float* __restrict__ Cm) {
  int b = blockIdx.y, l0 = blockIdx.x * 64;
  __shared__ float xt[(64 + 3) * DIN];     // [l+3][d], row 0 == l0-3
  __shared__ float xst[64 * DIN];
  __shared__ float dt4[64 * 4];
  int t = threadIdx.x;
  for (int i = t; i < 67 * DIN; i += 256) {
    int lr = i / DIN, d = i % DIN;
    int l = l0 - 3 + lr;
    xt[i] = (l >= 0) ? x[((size_t)b * LSEQ + l) * DIN + d] : 0.f;
  }
  __syncthreads();
  for (int i = t; i < 64 * DIN; i += 256) {
    int lr = i / DIN, d = i % DIN;
    const float* cw = conv_w + d * 4;
    float v = conv_b[d];
    v = fmaf(xt[(lr + 0) * DIN + d], cw[0], v);
    v = fmaf(xt[(lr + 1) * DIN + d], cw[1], v);
    v = fmaf(xt[(lr + 2) * DIN + d], cw[2], v);
    v = fmaf(xt[(lr + 3) * DIN + d], cw[3], v);
    v = siluf(v);
    xst[i] = v;
    xs[((size_t)b * LSEQ + l0 + lr) * DIN + d] = v;
  }
  __syncthreads();
  for (int task = t; task < 64 * 36; task += 256) {
    int lr = task / 36, j = task % 36;
    const float* wr = W_xproj + j * DIN;
    const float* xr = xst + lr * DIN;
    float a = 0.f;
    #pragma unroll 4
    for (int d = 0; d < DIN; d++) a = fmaf(xr[d], wr[d], a);
    size_t row = (size_t)b * LSEQ + l0 + lr;
    if (j < 4)       dt4[lr * 4 + j] = a;
    else if (j < 20) Bm[row * 16 + (j - 4)] = a;
    else             Cm[row * 16 + (j - 20)] = a;
  }
  __syncthreads();
  for (int i = t; i < 64 * DIN; i += 256) {
    int lr = i / DIN, d = i % DIN;
    float a = b_dt[d];
    const float* wd = W_dt + d * 4;
    const float* dr = dt4 + lr * 4;
    a = fmaf(dr[0], wd[0], a);
    a = fmaf(dr[1], wd[1], a);
    a = fmaf(dr[2], wd[2], a);
    a = fmaf(dr[3], wd[3], a);
    dt[((size_t)b * LSEQ + l0 + lr) * DIN + d] = softplusf(a);
  }
}

// ---------------- K5a: scan chunk aggregates (block per (b,chunk), row-streaming) ----
// thread t: d = t>>1, half = t&1, handles s = half*8 .. half*8+7 (8 states)
// aggregate layout: [chunk][ (b*128+d)*16 + s ]  -> fully coalesced
__global__ void k_scanA(const float* __restrict__ dt, const float* __restrict__ Bmat,
                        const float* __restrict__ xs, const float* __restrict__ A_log,
                        float* __restrict__ Ap, float* __restrict__ Bg) {
  int blk = blockIdx.x;            // 0..255
  int b = blk >> 7, chunk = blk & 127;
  int t = threadIdx.x;
  int d = t >> 1, half = t & 1;
  const float* al = A_log + d * 16 + half * 8;
  float a[8];
  #pragma unroll
  for (int j = 0; j < 8; j++) a[j] = -__expf(al[j]);
  size_t base = (size_t)b * LSEQ + chunk * CTL;
  float h[8], ap[8];
  #pragma unroll
  for (int j = 0; j < 8; j++) { h[j] = 0.f; ap[j] = 1.f; }
  for (int i = 0; i < CTL; i++) {
    size_t row = base + i;
    float dtv = dt[row * DIN + d];
    float xv  = xs[row * DIN + d];
    const float4* b4 = (const float4*)(Bmat + row * 16 + half * 8);
    float4 b0 = b4[0], b1 = b4[1];
    float bv[8] = {b0.x, b0.y, b0.z, b0.w, b1.x, b1.y, b1.z, b1.w};
    float u = dtv * xv;
    #pragma unroll
    for (int j = 0; j < 8; j++) {
      float dA = __expf(dtv * a[j]);
      h[j]  = fmaf(dA, h[j], u * bv[j]);
      ap[j] *= dA;
    }
  }
  size_t idx = (size_t)chunk * NCHAIN + (size_t)(b * DIN + d) * 16 + half * 8;
  #pragma unroll
  for (int j = 0; j < 8; j++) { Ap[idx + j] = ap[j]; Bg[idx + j] = h[j]; }
}

// ---------------- K5b: sequential combine across chunks ----------------
__global__ void k_scanB(const float* __restrict__ Ap, const float* __restrict__ Bg,
                        float* __restrict__ hinit) {
  int chain = blockIdx.x * 256 + threadIdx.x;   // 0..4095
  float h = 0.f;
  for (int c = 0; c < NCH; c++) {
    size_t idx = (size_t)c * NCHAIN + chain;
    hinit[idx] = h;
    h = fmaf(Ap[idx], h, Bg[idx]);
  }
}

// ---------------- K5c: re-scan with init, reduce over s, gate ----------------
__global__ void k_scanC(const float* __restrict__ dt, const float* __restrict__ Bmat,
                        const float* __restrict__ Cmat, const float* __restrict__ xs,
                        const float* __restrict__ z, const float* __restrict__ A_log,
                        const float* __restrict__ Dp, const float* __restrict__ hinit,
                        float* __restrict__ y) {
  int blk = blockIdx.x;
  int b = blk >> 7, chunk = blk & 127;
  int t = threadIdx.x;
  int d = t >> 1, half = t & 1;
  const float* al = A_log + d * 16 + half * 8;
  float a[8];
  #pragma unroll
  for (int j = 0; j < 8; j++) a[j] = -__expf(al[j]);
  float dp = Dp[d];
  size_t base = (size_t)b * LSEQ + chunk * CTL;
  size_t hidx = (size_t)chunk * NCHAIN + (size_t)(b * DIN + d) * 16 + half * 8;
  float h[8];
  #pragma unroll
  for (int j = 0; j < 8; j++) h[j] = hinit[hidx + j];
  for (int i = 0; i < CTL; i++) {
    size_t row = base + i;
    float dtv = dt[row * DIN + d];
    float xv  = xs[row * DIN + d];
    const float4* b4 = (const float4*)(Bmat + row * 16 + half * 8);
    float4 b0 = b4[0], b1 = b4[1];
    const float4* c4 = (const float4*)(Cmat + row * 16 + half * 8);
    float4 c0 = c4[0], c1 = c4[1];
    float bv[8] = {b0.x, b0.y, b0.z, b0.w, b1.x, b1.y, b1.z, b1.w};
    float cv[8] = {c0.x, c0.y, c0.z, c0.w, c1.x, c1.y, c1.z, c1.w};
    float u = dtv * xv;
    float p = 0.f;
    #pragma unroll
    for (int j = 0; j < 8; j++) {
      float dA = __expf(dtv * a[j]);
      h[j] = fmaf(dA, h[j], u * bv[j]);
      p = fmaf(h[j], cv[j], p);
    }
    p += __shfl_xor(p, 1);
    if (half == 0) {
      float zv = z[row * DIN + d];
      y[row * DIN + d] = (p + xv * dp) * siluf(zv);
    }
  }
}

// ---------------- K6: out-proj + BN + GELU + residual + clip ----------------
__global__ void k_out(const float* __restrict__ y, const float* __restrict__ Mt,
                      const float* __restrict__ bp, const float* __restrict__ bn_g,
                      const float* __restrict__ bn_bt, const float* __restrict__ bn_m,
                      const float* __restrict__ bn_v, const float* __restrict__ res,
                      float* __restrict__ out) {
  int b = blockIdx.y, l0 = blockIdx.x * 64;
  int t = threadIdx.x;
  int c = t & 63, lg = t >> 6;
  __shared__ float tile[64][65];
  float acc[16];
  float bpc = bp[c];
  #pragma unroll
  for (int i = 0; i < 16; i++) acc[i] = bpc;
  const float* yb = y + ((size_t)b * LSEQ + l0 + lg * 16) * DIN;
  #pragma unroll 4
  for (int d = 0; d < DIN; d++) {
    float m = Mt[d * 64 + c];
    #pragma unroll
    for (int i = 0; i < 16; i++) acc[i] = fmaf(m, yb[i * DIN + d], acc[i]);
  }
  float g = bn_g[c], bt = bn_bt[c], mu = bn_m[c];
  float iv = rsqrtf(bn_v[c] + 1e-5f);
  #pragma unroll
  for (int i = 0; i < 16; i++) {
    float a = (acc[i] - mu) * iv * g + bt;
    a = 0.5f * a * (1.f + erff(a * 0.70710678118654752f));   // exact GELU
    tile[c][lg * 16 + i] = a;
  }
  __syncthreads();
  int l = t & 63, cg = t >> 6;
  #pragma unroll
  for (int i = 0; i < 16; i++) {
    int cc = cg * 16 + i;
    size_t idx = ((size_t)(b * DIMC + cc)) * LSEQ + l0 + l;
    out[idx] = clip10(res[idx] + tile[cc][l]);
  }
}

extern "C" void kernel_launch(void* const* d_in, const int* in_sizes, int n_in,
                              void* d_out, int out_size, void* d_ws, size_t ws_size,
                              hipStream_t stream) {
  const float* x       = (const float*)d_in[0];
  const float* gn_g    = (const float*)d_in[1];
  const float* gn_b    = (const float*)d_in[2];
  const float* W_in    = (const float*)d_in[3];
  const float* b_in    = (const float*)d_in[4];
  const float* conv_w  = (const float*)d_in[5];
  const float* conv_b  = (const float*)d_in[6];
  const float* W_xproj = (const float*)d_in[7];
  const float* W_dt    = (const float*)d_in[8];
  const float* b_dt    = (const float*)d_in[9];
  const float* A_log   = (const float*)d_in[10];
  const float* Dp      = (const float*)d_in[11];
  const float* W_out   = (const float*)d_in[12];
  const float* b_out   = (const float*)d_in[13];
  const float* proj_w  = (const float*)d_in[14];
  const float* proj_b  = (const float*)d_in[15];
  const float* bn_g    = (const float*)d_in[16];
  const float* bn_bt   = (const float*)d_in[17];
  const float* bn_m    = (const float*)d_in[18];
  const float* bn_v    = (const float*)d_in[19];

  float* ws = (float*)d_ws;
  float* sums = ws;                               // 64
  float* seq  = ws + 64;                          // 1179648  (B,L,C); dead after k_inproj
  float* res  = seq + 1179648;                    // 1179648  (B,C,L)
  float* xbuf = res + 1179648;                    // 2359296  (B,L,128) -> reused as y
  float* zbuf = xbuf + 2359296;                   // 2359296
  float* xsb  = zbuf + 2359296;                   // 2359296
  float* dtb  = xsb + 2359296;                    // 2359296
  float* Bmb  = dtb + 2359296;                    // 294912
  float* Cmb  = Bmb + 294912;                     // 294912
  float* Wt   = Cmb + 294912;                     // 16384
  float* Mt   = Wt + 16384;                       // 8192
  float* bp   = Mt + 8192;                        // 64
  float* hib  = bp + 64;                          // 524288 (NCH*NCHAIN)
  float* Apb  = seq;                              // 524288, reuses dead seq
  float* Bgb  = seq + 524288;                     // 524288, reuses dead seq
  float* ybuf = xbuf;                             // reuse: x consumed by k_conv_proj

  hipMemsetAsync(sums, 0, 64 * sizeof(float), stream);

  k_reduce<<<dim3(256, 2), 256, 0, stream>>>(x, sums);
  k_prep<<<97, 256, 0, stream>>>(W_in, proj_w, W_out, b_out, proj_b, Wt, Mt, bp);
  k_norm<<<dim3(144, 2), 256, 0, stream>>>(x, gn_g, gn_b, sums, seq, res);
  k_inproj<<<1152, 256, 0, stream>>>(seq, Wt, b_in, xbuf, zbuf);
  k_conv_proj<<<dim3(144, 2), 256, 0, stream>>>(xbuf, conv_w, conv_b, W_xproj, W_dt, b_dt,
                                                xsb, dtb, Bmb, Cmb);
  k_scanA<<<256, 256, 0, stream>>>(dtb, Bmb, xsb, A_log, Apb, Bgb);
  k_scanB<<<16, 256, 0, stream>>>(Apb, Bgb, hib);
  k_scanC<<<256, 256, 0, stream>>>(dtb, Bmb, Cmb, xsb, zbuf, A_log, Dp, hib, ybuf);
  k_out<<<dim3(144, 2), 256, 0, stream>>>(ybuf, Mt, bp, bn_g, bn_bt, bn_m, bn_v, res,
                                          (float*)d_out);
}

// Round 3
// 308.044 us; speedup vs baseline: 1.8416x; 1.1594x over previous
//
#include <hip/hip_runtime.h>
#include <math.h>

#define DIMC 64
#define DIN  128
#define LSEQ 9216
#define NPB  (DIMC*LSEQ)      // 589824 elements per batch
#define NCH  128              // scan chunks
#define CTL  72               // chunk length: NCH*CTL == LSEQ
#define NCHAIN 4096           // 2 batches * 128 d * 16 s
#define PADR 132              // padded row stride for conv tile (uniform bank coverage)

__device__ __forceinline__ float siluf(float v)    { return v / (1.f + __expf(-v)); }
__device__ __forceinline__ float softplusf(float v){ return (v > 20.f) ? v : log1pf(__expf(v)); }
__device__ __forceinline__ float clip10(float v)   { return fminf(10.f, fmaxf(-10.f, v)); }

// ---------------- K1: per-batch sum / sumsq ----------------
__global__ void k_reduce(const float* __restrict__ x, float* __restrict__ sums) {
  int b = blockIdx.y;
  const float* xb = x + (size_t)b * NPB;
  float s = 0.f, s2 = 0.f;
  for (int i = blockIdx.x * blockDim.x + threadIdx.x; i < NPB; i += gridDim.x * blockDim.x) {
    float v = xb[i]; s += v; s2 = fmaf(v, v, s2);
  }
  __shared__ float l1[256], l2[256];
  int t = threadIdx.x;
  l1[t] = s; l2[t] = s2; __syncthreads();
  for (int off = 128; off > 0; off >>= 1) {
    if (t < off) { l1[t] += l1[t + off]; l2[t] += l2[t + off]; }
    __syncthreads();
  }
  if (t == 0) { atomicAdd(&sums[2*b], l1[0]); atomicAdd(&sums[2*b+1], l2[0]); }
}

// ---------------- K2: normalize + clip; write res (B,C,L) and seq (B,L,C) ----------------
__global__ void k_norm(const float* __restrict__ x, const float* __restrict__ gam,
                       const float* __restrict__ bet, const float* __restrict__ sums,
                       float* __restrict__ seq, float* __restrict__ res) {
  int b = blockIdx.y, l0 = blockIdx.x * 64;
  float mean = sums[2*b] * (1.f / NPB);
  float var  = sums[2*b+1] * (1.f / NPB) - mean * mean;
  float inv  = rsqrtf(var + 1e-5f);
  __shared__ float tile[64][65];
  int t = threadIdx.x;
  int lr = t & 63, cg = t >> 6;
  #pragma unroll
  for (int i = 0; i < 16; i++) {
    int c = i * 4 + cg;
    size_t idx = ((size_t)(b * DIMC + c)) * LSEQ + l0 + lr;
    float v = x[idx];
    v = (v - mean) * inv * gam[c] + bet[c];
    v = clip10(v);
    res[idx] = v;
    tile[c][lr] = v;
  }
  __syncthreads();
  int cc = t & 63, lg = t >> 6;
  #pragma unroll
  for (int i = 0; i < 16; i++) {
    int l = i * 4 + lg;
    seq[((size_t)(b * LSEQ + l0 + l)) * DIMC + cc] = tile[cc][l];
  }
}

// ---------------- K2p: prep — transpose W_in; fold proj_w@W_out ----------------
__global__ void k_prep(const float* __restrict__ W_in, const float* __restrict__ proj_w,
                       const float* __restrict__ W_out, const float* __restrict__ b_out,
                       const float* __restrict__ proj_b,
                       float* __restrict__ Wt, float* __restrict__ Mt, float* __restrict__ bp) {
  int i = blockIdx.x * 256 + threadIdx.x;
  if (i < 16384) {                              // Wt[k*256+c] = W_in[c*64+k]
    int k = i >> 8, c = i & 255;
    Wt[i] = W_in[c * 64 + k];
    return;
  }
  int j = i - 16384;
  if (j < 8192) {                               // Mt[d*64+o] = sum_c proj_w[o,c]*W_out[c,d]
    int d = j >> 6, o = j & 63;
    float a = 0.f;
    for (int c = 0; c < 64; c++) a = fmaf(proj_w[o * 64 + c], W_out[c * DIN + d], a);
    Mt[j] = a;
    return;
  }
  int k2 = i - 24576;
  if (k2 < 64) {
    float a = proj_b[k2];
    for (int c = 0; c < 64; c++) a = fmaf(proj_w[k2 * 64 + c], b_out[c], a);
    bp[k2] = a;
  }
}

// ---------------- K3: in-proj GEMM: xz = seq @ W_in^T + b_in ----------------
__global__ void k_inproj(const float* __restrict__ seq, const float* __restrict__ Wt,
                         const float* __restrict__ b_in,
                         float* __restrict__ xo, float* __restrict__ zo) {
  int row0 = blockIdx.x * 16;
  int c = threadIdx.x;                       // 0..255 output column
  float acc[16];
  float bi = b_in[c];
  #pragma unroll
  for (int r = 0; r < 16; r++) acc[r] = bi;
  const float* sp = seq + (size_t)row0 * DIMC;
  #pragma unroll 4
  for (int k = 0; k < 64; k++) {
    float w = Wt[k * 256 + c];
    #pragma unroll
    for (int r = 0; r < 16; r++) acc[r] = fmaf(w, sp[r * 64 + k], acc[r]);
  }
  #pragma unroll
  for (int r = 0; r < 16; r++) {
    size_t rr = (size_t)(row0 + r);
    if (c < DIN) xo[rr * DIN + c] = acc[r];
    else         zo[rr * DIN + (c - DIN)] = acc[r];
  }
}

// ---------------- K4: depthwise conv+SiLU, x-proj(36), dt(128) — register version ----
// Block: 256 threads = 4 waves; tile = 64 rows.
// Phase C mapping: wave q (0..3) owns d in [32q, 32q+32); lane = row (0..63).
__global__ void k_conv_proj(const float* __restrict__ x, const float* __restrict__ conv_w,
                            const float* __restrict__ conv_b, const float* __restrict__ W_xproj,
                            const float* __restrict__ W_dt, const float* __restrict__ b_dt,
                            float* __restrict__ xs, float* __restrict__ dt,
                            float* __restrict__ Bm, float* __restrict__ Cm) {
  int b = blockIdx.y, l0 = blockIdx.x * 64;
  __shared__ float xt[67 * PADR];          // input tile + 3 halo rows, padded stride
  __shared__ float red[4 * 64 * 37];       // per-wave x-proj partials [w][lr][37]
  __shared__ float dt4[64 * 4];
  int t = threadIdx.x;

  // Phase A: cooperative tile load (coalesced global, conflict-free LDS)
  for (int i = t; i < 67 * 128; i += 256) {
    int lr = i >> 7, d = i & 127;
    int l = l0 - 3 + lr;
    xt[lr * PADR + d] = (l >= 0) ? x[((size_t)b * LSEQ + l) * DIN + d] : 0.f;
  }
  __syncthreads();

  // Phase C: conv+SiLU into registers, then x-proj with wave-uniform weights
  int q = t >> 6;                          // wave id == d-quarter
  int qu = __builtin_amdgcn_readfirstlane(q);   // provably wave-uniform
  int lr = t & 63;
  size_t row = (size_t)b * LSEQ + l0 + lr;
  const float* xtr = xt + lr * PADR + qu * 32;
  const float4* cw4 = (const float4*)conv_w;   // [d] -> 4 taps
  const float4* cb4 = (const float4*)conv_b;
  float xv[32];
  #pragma unroll
  for (int c = 0; c < 8; c++) {
    int dbase = qu * 32 + c * 4;
    float4 t0 = *(const float4*)(xtr + 0 * PADR + c * 4);
    float4 t1 = *(const float4*)(xtr + 1 * PADR + c * 4);
    float4 t2 = *(const float4*)(xtr + 2 * PADR + c * 4);
    float4 t3 = *(const float4*)(xtr + 3 * PADR + c * 4);
    float4 cb = cb4[qu * 8 + c];
    float4 w;
    float a0, a1, a2, a3;
    w = cw4[dbase + 0];
    a0 = cb.x; a0 = fmaf(t0.x, w.x, a0); a0 = fmaf(t1.x, w.y, a0);
    a0 = fmaf(t2.x, w.z, a0); a0 = fmaf(t3.x, w.w, a0); a0 = siluf(a0);
    w = cw4[dbase + 1];
    a1 = cb.y; a1 = fmaf(t0.y, w.x, a1); a1 = fmaf(t1.y, w.y, a1);
    a1 = fmaf(t2.y, w.z, a1); a1 = fmaf(t3.y, w.w, a1); a1 = siluf(a1);
    w = cw4[dbase + 2];
    a2 = cb.z; a2 = fmaf(t0.z, w.x, a2); a2 = fmaf(t1.z, w.y, a2);
    a2 = fmaf(t2.z, w.z, a2); a2 = fmaf(t3.z, w.w, a2); a2 = siluf(a2);
    w = cw4[dbase + 3];
    a3 = cb.w; a3 = fmaf(t0.w, w.x, a3); a3 = fmaf(t1.w, w.y, a3);
    a3 = fmaf(t2.w, w.z, a3); a3 = fmaf(t3.w, w.w, a3); a3 = siluf(a3);
    xv[c * 4 + 0] = a0; xv[c * 4 + 1] = a1; xv[c * 4 + 2] = a2; xv[c * 4 + 3] = a3;
    *(float4*)(xs + row * DIN + dbase) = make_float4(a0, a1, a2, a3);
  }

  // x-proj: 36 outputs, weights wave-uniform -> s_load; partials to LDS
  const float4* W4 = (const float4*)W_xproj;
  float* myred = red + (q * 64 + lr) * 37;
  for (int j = 0; j < 36; j++) {
    const float4* wr = W4 + j * 32 + qu * 8;
    float p0 = 0.f, p1 = 0.f;
    #pragma unroll
    for (int c = 0; c < 8; c += 2) {
      float4 w0 = wr[c], w1 = wr[c + 1];
      p0 = fmaf(xv[c * 4 + 0], w0.x, p0);
      p0 = fmaf(xv[c * 4 + 1], w0.y, p0);
      p0 = fmaf(xv[c * 4 + 2], w0.z, p0);
      p0 = fmaf(xv[c * 4 + 3], w0.w, p0);
      p1 = fmaf(xv[c * 4 + 4], w1.x, p1);
      p1 = fmaf(xv[c * 4 + 5], w1.y, p1);
      p1 = fmaf(xv[c * 4 + 6], w1.z, p1);
      p1 = fmaf(xv[c * 4 + 7], w1.w, p1);
    }
    myred[j] = p0 + p1;
  }
  __syncthreads();

  // Reduce across the 4 waves; scatter to dt4 / Bm / Cm
  for (int k = 0; k < 9; k++) {
    int task = t + k * 256;                // 2304 = 64 rows * 36 outputs
    int lrr = task / 36, j = task - lrr * 36;
    int o = lrr * 37 + j;
    float ssum = red[o] + red[2368 + o] + red[2 * 2368 + o] + red[3 * 2368 + o];
    size_t rrow = (size_t)b * LSEQ + l0 + lrr;
    if (j < 4)       dt4[lrr * 4 + j] = ssum;
    else if (j < 20) Bm[rrow * 16 + (j - 4)]  = ssum;
    else             Cm[rrow * 16 + (j - 20)] = ssum;
  }
  __syncthreads();

  // dt projection + softplus: thread (lr2, q2) covers 32 d
  int lr2 = t >> 2, q2 = t & 3;
  float4 dv = *(const float4*)(dt4 + lr2 * 4);
  size_t rrow = (size_t)b * LSEQ + l0 + lr2;
  const float4* Wd4 = (const float4*)W_dt;    // [d] -> 4 dt-rank weights
  const float4* bd4 = (const float4*)b_dt;
  #pragma unroll
  for (int c = 0; c < 8; c++) {
    int dd = q2 * 32 + c * 4;
    float4 bb = bd4[q2 * 8 + c];
    float4 w;
    float s0, s1, s2, s3;
    w = Wd4[dd + 0];
    s0 = bb.x; s0 = fmaf(dv.x, w.x, s0); s0 = fmaf(dv.y, w.y, s0);
    s0 = fmaf(dv.z, w.z, s0); s0 = fmaf(dv.w, w.w, s0);
    w = Wd4[dd + 1];
    s1 = bb.y; s1 = fmaf(dv.x, w.x, s1); s1 = fmaf(dv.y, w.y, s1);
    s1 = fmaf(dv.z, w.z, s1); s1 = fmaf(dv.w, w.w, s1);
    w = Wd4[dd + 2];
    s2 = bb.z; s2 = fmaf(dv.x, w.x, s2); s2 = fmaf(dv.y, w.y, s2);
    s2 = fmaf(dv.z, w.z, s2); s2 = fmaf(dv.w, w.w, s2);
    w = Wd4[dd + 3];
    s3 = bb.w; s3 = fmaf(dv.x, w.x, s3); s3 = fmaf(dv.y, w.y, s3);
    s3 = fmaf(dv.z, w.z, s3); s3 = fmaf(dv.w, w.w, s3);
    *(float4*)(dt + rrow * DIN + dd) =
        make_float4(softplusf(s0), softplusf(s1), softplusf(s2), softplusf(s3));
  }
}

// ---------------- K5a: scan chunk aggregates (block per (b,chunk), row-streaming) ----
__global__ void k_scanA(const float* __restrict__ dt, const float* __restrict__ Bmat,
                        const float* __restrict__ xs, const float* __restrict__ A_log,
                        float* __restrict__ Ap, float* __restrict__ Bg) {
  int blk = blockIdx.x;            // 0..255
  int b = blk >> 7, chunk = blk & 127;
  int t = threadIdx.x;
  int d = t >> 1, half = t & 1;
  const float* al = A_log + d * 16 + half * 8;
  float a[8];
  #pragma unroll
  for (int j = 0; j < 8; j++) a[j] = -__expf(al[j]);
  size_t base = (size_t)b * LSEQ + chunk * CTL;
  float h[8], ap[8];
  #pragma unroll
  for (int j = 0; j < 8; j++) { h[j] = 0.f; ap[j] = 1.f; }
  for (int i = 0; i < CTL; i++) {
    size_t row = base + i;
    float dtv = dt[row * DIN + d];
    float xv  = xs[row * DIN + d];
    const float4* b4 = (const float4*)(Bmat + row * 16 + half * 8);
    float4 b0 = b4[0], b1 = b4[1];
    float bv[8] = {b0.x, b0.y, b0.z, b0.w, b1.x, b1.y, b1.z, b1.w};
    float u = dtv * xv;
    #pragma unroll
    for (int j = 0; j < 8; j++) {
      float dA = __expf(dtv * a[j]);
      h[j]  = fmaf(dA, h[j], u * bv[j]);
      ap[j] *= dA;
    }
  }
  size_t idx = (size_t)chunk * NCHAIN + (size_t)(b * DIN + d) * 16 + half * 8;
  #pragma unroll
  for (int j = 0; j < 8; j++) { Ap[idx + j] = ap[j]; Bg[idx + j] = h[j]; }
}

// ---------------- K5b: sequential combine across chunks ----------------
__global__ void k_scanB(const float* __restrict__ Ap, const float* __restrict__ Bg,
                        float* __restrict__ hinit) {
  int chain = blockIdx.x * 256 + threadIdx.x;   // 0..4095
  float h = 0.f;
  for (int c = 0; c < NCH; c++) {
    size_t idx = (size_t)c * NCHAIN + chain;
    hinit[idx] = h;
    h = fmaf(Ap[idx], h, Bg[idx]);
  }
}

// ---------------- K5c: re-scan with init, reduce over s, gate ----------------
__global__ void k_scanC(const float* __restrict__ dt, const float* __restrict__ Bmat,
                        const float* __restrict__ Cmat, const float* __restrict__ xs,
                        const float* __restrict__ z, const float* __restrict__ A_log,
                        const float* __restrict__ Dp, const float* __restrict__ hinit,
                        float* __restrict__ y) {
  int blk = blockIdx.x;
  int b = blk >> 7, chunk = blk & 127;
  int t = threadIdx.x;
  int d = t >> 1, half = t & 1;
  const float* al = A_log + d * 16 + half * 8;
  float a[8];
  #pragma unroll
  for (int j = 0; j < 8; j++) a[j] = -__expf(al[j]);
  float dp = Dp[d];
  size_t base = (size_t)b * LSEQ + chunk * CTL;
  size_t hidx = (size_t)chunk * NCHAIN + (size_t)(b * DIN + d) * 16 + half * 8;
  float h[8];
  #pragma unroll
  for (int j = 0; j < 8; j++) h[j] = hinit[hidx + j];
  for (int i = 0; i < CTL; i++) {
    size_t row = base + i;
    float dtv = dt[row * DIN + d];
    float xv  = xs[row * DIN + d];
    const float4* b4 = (const float4*)(Bmat + row * 16 + half * 8);
    float4 b0 = b4[0], b1 = b4[1];
    const float4* c4 = (const float4*)(Cmat + row * 16 + half * 8);
    float4 c0 = c4[0], c1 = c4[1];
    float bv[8] = {b0.x, b0.y, b0.z, b0.w, b1.x, b1.y, b1.z, b1.w};
    float cv[8] = {c0.x, c0.y, c0.z, c0.w, c1.x, c1.y, c1.z, c1.w};
    float u = dtv * xv;
    float p = 0.f;
    #pragma unroll
    for (int j = 0; j < 8; j++) {
      float dA = __expf(dtv * a[j]);
      h[j] = fmaf(dA, h[j], u * bv[j]);
      p = fmaf(h[j], cv[j], p);
    }
    p += __shfl_xor(p, 1);
    if (half == 0) {
      float zv = z[row * DIN + d];
      y[row * DIN + d] = (p + xv * dp) * siluf(zv);
    }
  }
}

// ---------------- K6: out-proj + BN + GELU + residual + clip ----------------
__global__ void k_out(const float* __restrict__ y, const float* __restrict__ Mt,
                      const float* __restrict__ bp, const float* __restrict__ bn_g,
                      const float* __restrict__ bn_bt, const float* __restrict__ bn_m,
                      const float* __restrict__ bn_v, const float* __restrict__ res,
                      float* __restrict__ out) {
  int b = blockIdx.y, l0 = blockIdx.x * 64;
  int t = threadIdx.x;
  int c = t & 63, lg = t >> 6;
  __shared__ float tile[64][65];
  float acc[16];
  float bpc = bp[c];
  #pragma unroll
  for (int i = 0; i < 16; i++) acc[i] = bpc;
  const float* yb = y + ((size_t)b * LSEQ + l0 + lg * 16) * DIN;
  #pragma unroll 4
  for (int d = 0; d < DIN; d++) {
    float m = Mt[d * 64 + c];
    #pragma unroll
    for (int i = 0; i < 16; i++) acc[i] = fmaf(m, yb[i * DIN + d], acc[i]);
  }
  float g = bn_g[c], bt = bn_bt[c], mu = bn_m[c];
  float iv = rsqrtf(bn_v[c] + 1e-5f);
  #pragma unroll
  for (int i = 0; i < 16; i++) {
    float a = (acc[i] - mu) * iv * g + bt;
    a = 0.5f * a * (1.f + erff(a * 0.70710678118654752f));   // exact GELU
    tile[c][lg * 16 + i] = a;
  }
  __syncthreads();
  int l = t & 63, cg = t >> 6;
  #pragma unroll
  for (int i = 0; i < 16; i++) {
    int cc = cg * 16 + i;
    size_t idx = ((size_t)(b * DIMC + cc)) * LSEQ + l0 + l;
    out[idx] = clip10(res[idx] + tile[cc][l]);
  }
}

extern "C" void kernel_launch(void* const* d_in, const int* in_sizes, int n_in,
                              void* d_out, int out_size, void* d_ws, size_t ws_size,
                              hipStream_t stream) {
  const float* x       = (const float*)d_in[0];
  const float* gn_g    = (const float*)d_in[1];
  const float* gn_b    = (const float*)d_in[2];
  const float* W_in    = (const float*)d_in[3];
  const float* b_in    = (const float*)d_in[4];
  const float* conv_w  = (const float*)d_in[5];
  const float* conv_b  = (const float*)d_in[6];
  const float* W_xproj = (const float*)d_in[7];
  const float* W_dt    = (const float*)d_in[8];
  const float* b_dt    = (const float*)d_in[9];
  const float* A_log   = (const float*)d_in[10];
  const float* Dp      = (const float*)d_in[11];
  const float* W_out   = (const float*)d_in[12];
  const float* b_out   = (const float*)d_in[13];
  const float* proj_w  = (const float*)d_in[14];
  const float* proj_b  = (const float*)d_in[15];
  const float* bn_g    = (const float*)d_in[16];
  const float* bn_bt   = (const float*)d_in[17];
  const float* bn_m    = (const float*)d_in[18];
  const float* bn_v    = (const float*)d_in[19];

  float* ws = (float*)d_ws;
  float* sums = ws;                               // 64
  float* seq  = ws + 64;                          // 1179648  (B,L,C); dead after k_inproj
  float* res  = seq + 1179648;                    // 1179648  (B,C,L)
  float* xbuf = res + 1179648;                    // 2359296  (B,L,128) -> reused as y
  float* zbuf = xbuf + 2359296;                   // 2359296
  float* xsb  = zbuf + 2359296;                   // 2359296
  float* dtb  = xsb + 2359296;                    // 2359296
  float* Bmb  = dtb + 2359296;                    // 294912
  float* Cmb  = Bmb + 294912;                     // 294912
  float* Wt   = Cmb + 294912;                     // 16384
  float* Mt   = Wt + 16384;                       // 8192
  float* bp   = Mt + 8192;                        // 64
  float* hib  = bp + 64;                          // 524288 (NCH*NCHAIN)
  float* Apb  = seq;                              // 524288, reuses dead seq
  float* Bgb  = seq + 524288;                     // 524288, reuses dead seq
  float* ybuf = xbuf;                             // reuse: x consumed by k_conv_proj

  hipMemsetAsync(sums, 0, 64 * sizeof(float), stream);

  k_reduce<<<dim3(256, 2), 256, 0, stream>>>(x, sums);
  k_prep<<<97, 256, 0, stream>>>(W_in, proj_w, W_out, b_out, proj_b, Wt, Mt, bp);
  k_norm<<<dim3(144, 2), 256, 0, stream>>>(x, gn_g, gn_b, sums, seq, res);
  k_inproj<<<1152, 256, 0, stream>>>(seq, Wt, b_in, xbuf, zbuf);
  k_conv_proj<<<dim3(144, 2), 256, 0, stream>>>(xbuf, conv_w, conv_b, W_xproj, W_dt, b_dt,
                                                xsb, dtb, Bmb, Cmb);
  k_scanA<<<256, 256, 0, stream>>>(dtb, Bmb, xsb, A_log, Apb, Bgb);
  k_scanB<<<16, 256, 0, stream>>>(Apb, Bgb, hib);
  k_scanC<<<256, 256, 0, stream>>>(dtb, Bmb, Cmb, xsb, zbuf, A_log, Dp, hib, ybuf);
  k_out<<<dim3(144, 2), 256, 0, stream>>>(ybuf, Mt, bp, bn_g, bn_bt, bn_m, bn_v, res,
                                          (float*)d_out);
}

// Round 4
// 289.853 us; speedup vs baseline: 1.9571x; 1.0628x over previous
//
#include <hip/hip_runtime.h>
#include <math.h>

#define DIMC 64
#define DIN  128
#define LSEQ 9216
#define NPB  (DIMC*LSEQ)      // 589824 elements per batch
#define NCH  192              // scan chunks
#define CTL  48               // chunk length: NCH*CTL == LSEQ
#define NCHAIN 4096           // 2 batches * 128 d * 16 s
#define PADR 132              // padded row stride for conv tile (uniform bank coverage)

__device__ __forceinline__ float siluf(float v)    { return v / (1.f + __expf(-v)); }
__device__ __forceinline__ float softplusf(float v){ return (v > 20.f) ? v : log1pf(__expf(v)); }
__device__ __forceinline__ float clip10(float v)   { return fminf(10.f, fmaxf(-10.f, v)); }

// ---------------- K1: per-batch sum / sumsq ----------------
__global__ void k_reduce(const float* __restrict__ x, float* __restrict__ sums) {
  int b = blockIdx.y;
  const float* xb = x + (size_t)b * NPB;
  float s = 0.f, s2 = 0.f;
  for (int i = blockIdx.x * blockDim.x + threadIdx.x; i < NPB; i += gridDim.x * blockDim.x) {
    float v = xb[i]; s += v; s2 = fmaf(v, v, s2);
  }
  __shared__ float l1[256], l2[256];
  int t = threadIdx.x;
  l1[t] = s; l2[t] = s2; __syncthreads();
  for (int off = 128; off > 0; off >>= 1) {
    if (t < off) { l1[t] += l1[t + off]; l2[t] += l2[t + off]; }
    __syncthreads();
  }
  if (t == 0) { atomicAdd(&sums[2*b], l1[0]); atomicAdd(&sums[2*b+1], l2[0]); }
}

// ---------------- K2: normalize + clip; write res (B,C,L) and seq (B,L,C) ----------------
__global__ void k_norm(const float* __restrict__ x, const float* __restrict__ gam,
                       const float* __restrict__ bet, const float* __restrict__ sums,
                       float* __restrict__ seq, float* __restrict__ res) {
  int b = blockIdx.y, l0 = blockIdx.x * 64;
  float mean = sums[2*b] * (1.f / NPB);
  float var  = sums[2*b+1] * (1.f / NPB) - mean * mean;
  float inv  = rsqrtf(var + 1e-5f);
  __shared__ float tile[64][65];
  int t = threadIdx.x;
  int lr = t & 63, cg = t >> 6;
  #pragma unroll
  for (int i = 0; i < 16; i++) {
    int c = i * 4 + cg;
    size_t idx = ((size_t)(b * DIMC + c)) * LSEQ + l0 + lr;
    float v = x[idx];
    v = (v - mean) * inv * gam[c] + bet[c];
    v = clip10(v);
    res[idx] = v;
    tile[c][lr] = v;
  }
  __syncthreads();
  int cc = t & 63, lg = t >> 6;
  #pragma unroll
  for (int i = 0; i < 16; i++) {
    int l = i * 4 + lg;
    seq[((size_t)(b * LSEQ + l0 + l)) * DIMC + cc] = tile[cc][l];
  }
}

// ---------------- K2p: prep — transpose W_in; fold proj_w@W_out ----------------
__global__ void k_prep(const float* __restrict__ W_in, const float* __restrict__ proj_w,
                       const float* __restrict__ W_out, const float* __restrict__ b_out,
                       const float* __restrict__ proj_b,
                       float* __restrict__ Wt, float* __restrict__ Mt, float* __restrict__ bp) {
  int i = blockIdx.x * 256 + threadIdx.x;
  if (i < 16384) {                              // Wt[k*256+c] = W_in[c*64+k]
    int k = i >> 8, c = i & 255;
    Wt[i] = W_in[c * 64 + k];
    return;
  }
  int j = i - 16384;
  if (j < 8192) {                               // Mt[d*64+o] = sum_c proj_w[o,c]*W_out[c,d]
    int d = j >> 6, o = j & 63;
    float a = 0.f;
    for (int c = 0; c < 64; c++) a = fmaf(proj_w[o * 64 + c], W_out[c * DIN + d], a);
    Mt[j] = a;
    return;
  }
  int k2 = i - 24576;
  if (k2 < 64) {
    float a = proj_b[k2];
    for (int c = 0; c < 64; c++) a = fmaf(proj_w[k2 * 64 + c], b_out[c], a);
    bp[k2] = a;
  }
}

// ---------------- K3: in-proj GEMM: xz = seq @ W_in^T + b_in ----------------
__global__ void k_inproj(const float* __restrict__ seq, const float* __restrict__ Wt,
                         const float* __restrict__ b_in,
                         float* __restrict__ xo, float* __restrict__ zo) {
  int row0 = blockIdx.x * 16;
  int c = threadIdx.x;                       // 0..255 output column
  float acc[16];
  float bi = b_in[c];
  #pragma unroll
  for (int r = 0; r < 16; r++) acc[r] = bi;
  const float* sp = seq + (size_t)row0 * DIMC;
  #pragma unroll 4
  for (int k = 0; k < 64; k++) {
    float w = Wt[k * 256 + c];
    #pragma unroll
    for (int r = 0; r < 16; r++) acc[r] = fmaf(w, sp[r * 64 + k], acc[r]);
  }
  #pragma unroll
  for (int r = 0; r < 16; r++) {
    size_t rr = (size_t)(row0 + r);
    if (c < DIN) xo[rr * DIN + c] = acc[r];
    else         zo[rr * DIN + (c - DIN)] = acc[r];
  }
}

// ---------------- K4: depthwise conv+SiLU, x-proj(36), dt(128) — register version ----
__global__ void k_conv_proj(const float* __restrict__ x, const float* __restrict__ conv_w,
                            const float* __restrict__ conv_b, const float* __restrict__ W_xproj,
                            const float* __restrict__ W_dt, const float* __restrict__ b_dt,
                            float* __restrict__ xs, float* __restrict__ dt,
                            float* __restrict__ Bm, float* __restrict__ Cm) {
  int b = blockIdx.y, l0 = blockIdx.x * 64;
  __shared__ float xt[67 * PADR];          // input tile + 3 halo rows, padded stride
  __shared__ float red[4 * 64 * 37];       // per-wave x-proj partials [w][lr][37]
  __shared__ float dt4[64 * 4];
  int t = threadIdx.x;

  for (int i = t; i < 67 * 128; i += 256) {
    int lr = i >> 7, d = i & 127;
    int l = l0 - 3 + lr;
    xt[lr * PADR + d] = (l >= 0) ? x[((size_t)b * LSEQ + l) * DIN + d] : 0.f;
  }
  __syncthreads();

  int q = t >> 6;                          // wave id == d-quarter
  int qu = __builtin_amdgcn_readfirstlane(q);
  int lr = t & 63;
  size_t row = (size_t)b * LSEQ + l0 + lr;
  const float* xtr = xt + lr * PADR + qu * 32;
  const float4* cw4 = (const float4*)conv_w;
  const float4* cb4 = (const float4*)conv_b;
  float xv[32];
  #pragma unroll
  for (int c = 0; c < 8; c++) {
    int dbase = qu * 32 + c * 4;
    float4 t0 = *(const float4*)(xtr + 0 * PADR + c * 4);
    float4 t1 = *(const float4*)(xtr + 1 * PADR + c * 4);
    float4 t2 = *(const float4*)(xtr + 2 * PADR + c * 4);
    float4 t3 = *(const float4*)(xtr + 3 * PADR + c * 4);
    float4 cb = cb4[qu * 8 + c];
    float4 w;
    float a0, a1, a2, a3;
    w = cw4[dbase + 0];
    a0 = cb.x; a0 = fmaf(t0.x, w.x, a0); a0 = fmaf(t1.x, w.y, a0);
    a0 = fmaf(t2.x, w.z, a0); a0 = fmaf(t3.x, w.w, a0); a0 = siluf(a0);
    w = cw4[dbase + 1];
    a1 = cb.y; a1 = fmaf(t0.y, w.x, a1); a1 = fmaf(t1.y, w.y, a1);
    a1 = fmaf(t2.y, w.z, a1); a1 = fmaf(t3.y, w.w, a1); a1 = siluf(a1);
    w = cw4[dbase + 2];
    a2 = cb.z; a2 = fmaf(t0.z, w.x, a2); a2 = fmaf(t1.z, w.y, a2);
    a2 = fmaf(t2.z, w.z, a2); a2 = fmaf(t3.z, w.w, a2); a2 = siluf(a2);
    w = cw4[dbase + 3];
    a3 = cb.w; a3 = fmaf(t0.w, w.x, a3); a3 = fmaf(t1.w, w.y, a3);
    a3 = fmaf(t2.w, w.z, a3); a3 = fmaf(t3.w, w.w, a3); a3 = siluf(a3);
    xv[c * 4 + 0] = a0; xv[c * 4 + 1] = a1; xv[c * 4 + 2] = a2; xv[c * 4 + 3] = a3;
    *(float4*)(xs + row * DIN + dbase) = make_float4(a0, a1, a2, a3);
  }

  const float4* W4 = (const float4*)W_xproj;
  float* myred = red + (q * 64 + lr) * 37;
  for (int j = 0; j < 36; j++) {
    const float4* wr = W4 + j * 32 + qu * 8;
    float p0 = 0.f, p1 = 0.f;
    #pragma unroll
    for (int c = 0; c < 8; c += 2) {
      float4 w0 = wr[c], w1 = wr[c + 1];
      p0 = fmaf(xv[c * 4 + 0], w0.x, p0);
      p0 = fmaf(xv[c * 4 + 1], w0.y, p0);
      p0 = fmaf(xv[c * 4 + 2], w0.z, p0);
      p0 = fmaf(xv[c * 4 + 3], w0.w, p0);
      p1 = fmaf(xv[c * 4 + 4], w1.x, p1);
      p1 = fmaf(xv[c * 4 + 5], w1.y, p1);
      p1 = fmaf(xv[c * 4 + 6], w1.z, p1);
      p1 = fmaf(xv[c * 4 + 7], w1.w, p1);
    }
    myred[j] = p0 + p1;
  }
  __syncthreads();

  for (int k = 0; k < 9; k++) {
    int task = t + k * 256;                // 2304 = 64 rows * 36 outputs
    int lrr = task / 36, j = task - lrr * 36;
    int o = lrr * 37 + j;
    float ssum = red[o] + red[2368 + o] + red[2 * 2368 + o] + red[3 * 2368 + o];
    size_t rrow = (size_t)b * LSEQ + l0 + lrr;
    if (j < 4)       dt4[lrr * 4 + j] = ssum;
    else if (j < 20) Bm[rrow * 16 + (j - 4)]  = ssum;
    else             Cm[rrow * 16 + (j - 20)] = ssum;
  }
  __syncthreads();

  int lr2 = t >> 2, q2 = t & 3;
  float4 dv = *(const float4*)(dt4 + lr2 * 4);
  size_t rrow = (size_t)b * LSEQ + l0 + lr2;
  const float4* Wd4 = (const float4*)W_dt;
  const float4* bd4 = (const float4*)b_dt;
  #pragma unroll
  for (int c = 0; c < 8; c++) {
    int dd = q2 * 32 + c * 4;
    float4 bb = bd4[q2 * 8 + c];
    float4 w;
    float s0, s1, s2, s3;
    w = Wd4[dd + 0];
    s0 = bb.x; s0 = fmaf(dv.x, w.x, s0); s0 = fmaf(dv.y, w.y, s0);
    s0 = fmaf(dv.z, w.z, s0); s0 = fmaf(dv.w, w.w, s0);
    w = Wd4[dd + 1];
    s1 = bb.y; s1 = fmaf(dv.x, w.x, s1); s1 = fmaf(dv.y, w.y, s1);
    s1 = fmaf(dv.z, w.z, s1); s1 = fmaf(dv.w, w.w, s1);
    w = Wd4[dd + 2];
    s2 = bb.z; s2 = fmaf(dv.x, w.x, s2); s2 = fmaf(dv.y, w.y, s2);
    s2 = fmaf(dv.z, w.z, s2); s2 = fmaf(dv.w, w.w, s2);
    w = Wd4[dd + 3];
    s3 = bb.w; s3 = fmaf(dv.x, w.x, s3); s3 = fmaf(dv.y, w.y, s3);
    s3 = fmaf(dv.z, w.z, s3); s3 = fmaf(dv.w, w.w, s3);
    *(float4*)(dt + rrow * DIN + dd) =
        make_float4(softplusf(s0), softplusf(s1), softplusf(s2), softplusf(s3));
  }
}

// ---------------- K5a: scan chunk aggregates -------------------------------
// grid (NCH, 2), 512 threads: d = t>>2, quarter = t&3 (4 states each).
// Fully scalarized state -> registers, no scratch.
__global__ void __launch_bounds__(512) k_scanA(
    const float* __restrict__ dt, const float* __restrict__ Bmat,
    const float* __restrict__ xs, const float* __restrict__ A_log,
    float* __restrict__ Ap, float* __restrict__ Bg) {
  int chunk = blockIdx.x, b = blockIdx.y;
  int t = threadIdx.x;
  int d = t >> 2, q = t & 3;
  const float* al = A_log + d * 16 + q * 4;
  float a0 = -__expf(al[0]), a1 = -__expf(al[1]);
  float a2 = -__expf(al[2]), a3 = -__expf(al[3]);
  size_t base = (size_t)b * LSEQ + (size_t)chunk * CTL;
  const float* dtp = dt + base * DIN + d;
  const float* xsp = xs + base * DIN + d;
  const float4* bp4 = (const float4*)(Bmat + base * 16 + q * 4);
  float h0 = 0.f, h1 = 0.f, h2 = 0.f, h3 = 0.f;
  float p0 = 1.f, p1 = 1.f, p2 = 1.f, p3 = 1.f;
  #pragma unroll 4
  for (int i = 0; i < CTL; i++) {
    float dtv = dtp[(size_t)i * DIN];
    float xv  = xsp[(size_t)i * DIN];
    float4 bA = bp4[i * 4];
    float u = dtv * xv;
    float e;
    e = __expf(dtv * a0); h0 = fmaf(e, h0, u * bA.x); p0 *= e;
    e = __expf(dtv * a1); h1 = fmaf(e, h1, u * bA.y); p1 *= e;
    e = __expf(dtv * a2); h2 = fmaf(e, h2, u * bA.z); p2 *= e;
    e = __expf(dtv * a3); h3 = fmaf(e, h3, u * bA.w); p3 *= e;
  }
  size_t idx = (size_t)chunk * NCHAIN + (size_t)(b * DIN + d) * 16 + q * 4;
  *(float4*)(Ap + idx) = make_float4(p0, p1, p2, p3);
  *(float4*)(Bg + idx) = make_float4(h0, h1, h2, h3);
}

// ---------------- K5b: sequential combine across chunks ----------------
__global__ void k_scanB(const float* __restrict__ Ap, const float* __restrict__ Bg,
                        float* __restrict__ hinit) {
  int chain = blockIdx.x * 64 + threadIdx.x;   // 0..4095
  float h = 0.f;
  for (int c = 0; c < NCH; c++) {
    size_t idx = (size_t)c * NCHAIN + chain;
    hinit[idx] = h;
    h = fmaf(Ap[idx], h, Bg[idx]);
  }
}

// ---------------- K5c: re-scan with init, reduce over s, gate ----------------
__global__ void __launch_bounds__(512) k_scanC(
    const float* __restrict__ dt, const float* __restrict__ Bmat,
    const float* __restrict__ Cmat, const float* __restrict__ xs,
    const float* __restrict__ z, const float* __restrict__ A_log,
    const float* __restrict__ Dp, const float* __restrict__ hinit,
    float* __restrict__ y) {
  int chunk = blockIdx.x, b = blockIdx.y;
  int t = threadIdx.x;
  int d = t >> 2, q = t & 3;
  const float* al = A_log + d * 16 + q * 4;
  float a0 = -__expf(al[0]), a1 = -__expf(al[1]);
  float a2 = -__expf(al[2]), a3 = -__expf(al[3]);
  float dp = Dp[d];
  size_t base = (size_t)b * LSEQ + (size_t)chunk * CTL;
  const float* dtp = dt + base * DIN + d;
  const float* xsp = xs + base * DIN + d;
  const float* zp  = z  + base * DIN + d;
  float* yp        = y  + base * DIN + d;
  const float4* bp4 = (const float4*)(Bmat + base * 16 + q * 4);
  const float4* cp4 = (const float4*)(Cmat + base * 16 + q * 4);
  size_t idx = (size_t)chunk * NCHAIN + (size_t)(b * DIN + d) * 16 + q * 4;
  float4 hv = *(const float4*)(hinit + idx);
  float h0 = hv.x, h1 = hv.y, h2 = hv.z, h3 = hv.w;
  #pragma unroll 2
  for (int i = 0; i < CTL; i++) {
    float dtv = dtp[(size_t)i * DIN];
    float xv  = xsp[(size_t)i * DIN];
    float4 bA = bp4[i * 4];
    float4 cA = cp4[i * 4];
    float u = dtv * xv;
    float e, p;
    e = __expf(dtv * a0); h0 = fmaf(e, h0, u * bA.x); p  = h0 * cA.x;
    e = __expf(dtv * a1); h1 = fmaf(e, h1, u * bA.y); p  = fmaf(h1, cA.y, p);
    e = __expf(dtv * a2); h2 = fmaf(e, h2, u * bA.z); p  = fmaf(h2, cA.z, p);
    e = __expf(dtv * a3); h3 = fmaf(e, h3, u * bA.w); p  = fmaf(h3, cA.w, p);
    p += __shfl_xor(p, 1);
    p += __shfl_xor(p, 2);
    if (q == 0) {
      float zv = zp[(size_t)i * DIN];
      yp[(size_t)i * DIN] = (p + xv * dp) * siluf(zv);
    }
  }
}

// ---------------- K6: out-proj + BN + GELU + residual + clip ----------------
__global__ void k_out(const float* __restrict__ y, const float* __restrict__ Mt,
                      const float* __restrict__ bp, const float* __restrict__ bn_g,
                      const float* __restrict__ bn_bt, const float* __restrict__ bn_m,
                      const float* __restrict__ bn_v, const float* __restrict__ res,
                      float* __restrict__ out) {
  int b = blockIdx.y, l0 = blockIdx.x * 64;
  int t = threadIdx.x;
  int c = t & 63, lg = t >> 6;
  __shared__ float tile[64][65];
  float acc[16];
  float bpc = bp[c];
  #pragma unroll
  for (int i = 0; i < 16; i++) acc[i] = bpc;
  const float* yb = y + ((size_t)b * LSEQ + l0 + lg * 16) * DIN;
  #pragma unroll 4
  for (int d = 0; d < DIN; d++) {
    float m = Mt[d * 64 + c];
    #pragma unroll
    for (int i = 0; i < 16; i++) acc[i] = fmaf(m, yb[i * DIN + d], acc[i]);
  }
  float g = bn_g[c], bt = bn_bt[c], mu = bn_m[c];
  float iv = rsqrtf(bn_v[c] + 1e-5f);
  #pragma unroll
  for (int i = 0; i < 16; i++) {
    float a = (acc[i] - mu) * iv * g + bt;
    a = 0.5f * a * (1.f + erff(a * 0.70710678118654752f));   // exact GELU
    tile[c][lg * 16 + i] = a;
  }
  __syncthreads();
  int l = t & 63, cg = t >> 6;
  #pragma unroll
  for (int i = 0; i < 16; i++) {
    int cc = cg * 16 + i;
    size_t idx = ((size_t)(b * DIMC + cc)) * LSEQ + l0 + l;
    out[idx] = clip10(res[idx] + tile[cc][l]);
  }
}

extern "C" void kernel_launch(void* const* d_in, const int* in_sizes, int n_in,
                              void* d_out, int out_size, void* d_ws, size_t ws_size,
                              hipStream_t stream) {
  const float* x       = (const float*)d_in[0];
  const float* gn_g    = (const float*)d_in[1];
  const float* gn_b    = (const float*)d_in[2];
  const float* W_in    = (const float*)d_in[3];
  const float* b_in    = (const float*)d_in[4];
  const float* conv_w  = (const float*)d_in[5];
  const float* conv_b  = (const float*)d_in[6];
  const float* W_xproj = (const float*)d_in[7];
  const float* W_dt    = (const float*)d_in[8];
  const float* b_dt    = (const float*)d_in[9];
  const float* A_log   = (const float*)d_in[10];
  const float* Dp      = (const float*)d_in[11];
  const float* W_out   = (const float*)d_in[12];
  const float* b_out   = (const float*)d_in[13];
  const float* proj_w  = (const float*)d_in[14];
  const float* proj_b  = (const float*)d_in[15];
  const float* bn_g    = (const float*)d_in[16];
  const float* bn_bt   = (const float*)d_in[17];
  const float* bn_m    = (const float*)d_in[18];
  const float* bn_v    = (const float*)d_in[19];

  float* ws = (float*)d_ws;
  float* sums = ws;                               // 64
  float* seq  = ws + 64;                          // 1179648  (B,L,C); dead after k_inproj
  float* res  = seq + 1179648;                    // 1179648  (B,C,L)
  float* xbuf = res + 1179648;                    // 2359296  (B,L,128) -> reused as y
  float* zbuf = xbuf + 2359296;                   // 2359296
  float* xsb  = zbuf + 2359296;                   // 2359296
  float* dtb  = xsb + 2359296;                    // 2359296
  float* Bmb  = dtb + 2359296;                    // 294912
  float* Cmb  = Bmb + 294912;                     // 294912
  float* Wt   = Cmb + 294912;                     // 16384
  float* Mt   = Wt + 16384;                       // 8192
  float* bp   = Mt + 8192;                        // 64
  float* Bgb  = bp + 64;                          // 786432 (NCH*NCHAIN)
  float* hib  = Bgb + 786432;                     // 786432
  float* Apb  = seq;                              // 786432, reuses dead seq
  float* ybuf = xbuf;                             // reuse: x consumed by k_conv_proj

  hipMemsetAsync(sums, 0, 64 * sizeof(float), stream);

  k_reduce<<<dim3(256, 2), 256, 0, stream>>>(x, sums);
  k_prep<<<97, 256, 0, stream>>>(W_in, proj_w, W_out, b_out, proj_b, Wt, Mt, bp);
  k_norm<<<dim3(144, 2), 256, 0, stream>>>(x, gn_g, gn_b, sums, seq, res);
  k_inproj<<<1152, 256, 0, stream>>>(seq, Wt, b_in, xbuf, zbuf);
  k_conv_proj<<<dim3(144, 2), 256, 0, stream>>>(xbuf, conv_w, conv_b, W_xproj, W_dt, b_dt,
                                                xsb, dtb, Bmb, Cmb);
  k_scanA<<<dim3(NCH, 2), 512, 0, stream>>>(dtb, Bmb, xsb, A_log, Apb, Bgb);
  k_scanB<<<64, 64, 0, stream>>>(Apb, Bgb, hib);
  k_scanC<<<dim3(NCH, 2), 512, 0, stream>>>(dtb, Bmb, Cmb, xsb, zbuf, A_log, Dp, hib, ybuf);
  k_out<<<dim3(144, 2), 256, 0, stream>>>(ybuf, Mt, bp, bn_g, bn_bt, bn_m, bn_v, res,
                                          (float*)d_out);
}

// Round 5
// 284.277 us; speedup vs baseline: 1.9955x; 1.0196x over previous
//
#include <hip/hip_runtime.h>
#include <math.h>

#define DIMC 64
#define DIN  128
#define LSEQ 9216
#define NPB  (DIMC*LSEQ)      // 589824 elements per batch
#define NCH  192              // scan chunks
#define CTL  48               // chunk length: NCH*CTL == LSEQ
#define NCHAIN 4096           // 2 batches * 128 d * 16 s

__device__ __forceinline__ float siluf(float v)    { return v / (1.f + __expf(-v)); }
__device__ __forceinline__ float softplusf(float v){ return (v > 20.f) ? v : log1pf(__expf(v)); }
__device__ __forceinline__ float clip10(float v)   { return fminf(10.f, fmaxf(-10.f, v)); }

// ---------------- K1: per-batch sum / sumsq ----------------
__global__ void k_reduce(const float* __restrict__ x, float* __restrict__ sums) {
  int b = blockIdx.y;
  const float* xb = x + (size_t)b * NPB;
  float s = 0.f, s2 = 0.f;
  for (int i = blockIdx.x * blockDim.x + threadIdx.x; i < NPB; i += gridDim.x * blockDim.x) {
    float v = xb[i]; s += v; s2 = fmaf(v, v, s2);
  }
  __shared__ float l1[256], l2[256];
  int t = threadIdx.x;
  l1[t] = s; l2[t] = s2; __syncthreads();
  for (int off = 128; off > 0; off >>= 1) {
    if (t < off) { l1[t] += l1[t + off]; l2[t] += l2[t + off]; }
    __syncthreads();
  }
  if (t == 0) { atomicAdd(&sums[2*b], l1[0]); atomicAdd(&sums[2*b+1], l2[0]); }
}

// ---------------- K2: normalize + clip; write res (B,C,L) and seq (B,L,C) ----------------
__global__ void k_norm(const float* __restrict__ x, const float* __restrict__ gam,
                       const float* __restrict__ bet, const float* __restrict__ sums,
                       float* __restrict__ seq, float* __restrict__ res) {
  int b = blockIdx.y, l0 = blockIdx.x * 64;
  float mean = sums[2*b] * (1.f / NPB);
  float var  = sums[2*b+1] * (1.f / NPB) - mean * mean;
  float inv  = rsqrtf(var + 1e-5f);
  __shared__ float tile[64][65];
  int t = threadIdx.x;
  int lr = t & 63, cg = t >> 6;
  #pragma unroll
  for (int i = 0; i < 16; i++) {
    int c = i * 4 + cg;
    size_t idx = ((size_t)(b * DIMC + c)) * LSEQ + l0 + lr;
    float v = x[idx];
    v = (v - mean) * inv * gam[c] + bet[c];
    v = clip10(v);
    res[idx] = v;
    tile[c][lr] = v;
  }
  __syncthreads();
  int cc = t & 63, lg = t >> 6;
  #pragma unroll
  for (int i = 0; i < 16; i++) {
    int l = i * 4 + lg;
    seq[((size_t)(b * LSEQ + l0 + l)) * DIMC + cc] = tile[cc][l];
  }
}

// ---------------- K2p: prep — transpose W_in; fold proj_w@W_out; build W_big ----------
// W_big (160 x 128): rows 0..127 = W_dt @ W_xproj[:4]  (dt path, bias b_dt)
//                    rows 128..143 = W_xproj[4..19] (B), rows 144..159 = W_xproj[20..35] (C)
// stored transposed: Wbt[k*160 + c]
__global__ void k_prep(const float* __restrict__ W_in, const float* __restrict__ proj_w,
                       const float* __restrict__ W_out, const float* __restrict__ b_out,
                       const float* __restrict__ proj_b, const float* __restrict__ W_xproj,
                       const float* __restrict__ W_dt, const float* __restrict__ b_dt,
                       float* __restrict__ Wt, float* __restrict__ Mt, float* __restrict__ bp,
                       float* __restrict__ Wbt, float* __restrict__ bbig) {
  int i = blockIdx.x * 256 + threadIdx.x;
  if (i < 16384) {                              // Wt[k*256+c] = W_in[c*64+k]
    int k = i >> 8, c = i & 255;
    Wt[i] = W_in[c * 64 + k];
    return;
  }
  int j = i - 16384;
  if (j < 8192) {                               // Mt[d*64+o] = sum_c proj_w[o,c]*W_out[c,d]
    int d = j >> 6, o = j & 63;
    float a = 0.f;
    for (int c = 0; c < 64; c++) a = fmaf(proj_w[o * 64 + c], W_out[c * DIN + d], a);
    Mt[j] = a;
    return;
  }
  int k2 = j - 8192;
  if (k2 < 64) {
    float a = proj_b[k2];
    for (int c = 0; c < 64; c++) a = fmaf(proj_w[k2 * 64 + c], b_out[c], a);
    bp[k2] = a;
    return;
  }
  int m = j - 8256;
  if (m < 20480) {                              // Wbt[k*160+c]
    int k = m / 160, c = m - k * 160;
    float v;
    if (c < 128) {
      v = 0.f;
      #pragma unroll
      for (int r = 0; r < 4; r++) v = fmaf(W_dt[c * 4 + r], W_xproj[r * DIN + k], v);
    } else {
      v = W_xproj[(c - 124) * DIN + k];         // c-128+4
    }
    Wbt[m] = v;
    return;
  }
  int c3 = m - 20480;
  if (c3 < 160) bbig[c3] = (c3 < 128) ? b_dt[c3] : 0.f;
}

// ---------------- K3: fused in-proj GEMM + depthwise conv + SiLU ----------------
// Block: 16 output rows (+3 halo rows recomputed), 256 threads = 1 col each.
// cols 0..127: x-half -> conv over the thread's own 19-row column -> SiLU -> xs
// cols 128..255: z-half -> zo
__global__ void k_inproj_conv(const float* __restrict__ seq, const float* __restrict__ Wt,
                              const float* __restrict__ b_in, const float* __restrict__ conv_w,
                              const float* __restrict__ conv_b,
                              float* __restrict__ xs, float* __restrict__ zo) {
  int row0 = blockIdx.x * 16;
  int l0 = row0 % LSEQ;                       // 0 only at a batch start
  int t = threadIdx.x;
  __shared__ float sq[19 * 64];               // seq rows row0-3 .. row0+15
  // cooperative stage (clamp negative rows; their values get masked later)
  for (int i = t; i < 19 * 16; i += 256) {    // float4 granularity: 19*64/4
    int r = i >> 4, k4 = i & 15;
    int rr = row0 - 3 + r; if (rr < 0) rr = 0;
    *(float4*)(sq + r * 64 + k4 * 4) = *(const float4*)(seq + (size_t)rr * DIMC + k4 * 4);
  }
  __syncthreads();

  int c = t;
  float bi = b_in[c];
  float a[19];
  #pragma unroll
  for (int r = 0; r < 19; r++) a[r] = bi;
  const float4* sq4 = (const float4*)sq;
  #pragma unroll 4
  for (int k4 = 0; k4 < 16; k4++) {
    float w0 = Wt[(k4 * 4 + 0) * 256 + c];
    float w1 = Wt[(k4 * 4 + 1) * 256 + c];
    float w2 = Wt[(k4 * 4 + 2) * 256 + c];
    float w3 = Wt[(k4 * 4 + 3) * 256 + c];
    #pragma unroll
    for (int r = 0; r < 19; r++) {
      float4 v = sq4[r * 16 + k4];
      a[r] = fmaf(w0, v.x, a[r]);
      a[r] = fmaf(w1, v.y, a[r]);
      a[r] = fmaf(w2, v.z, a[r]);
      a[r] = fmaf(w3, v.w, a[r]);
    }
  }
  if (c < DIN) {
    if (l0 == 0) { a[0] = 0.f; a[1] = 0.f; a[2] = 0.f; }   // causal zero-pad at batch start
    float4 cw = *(const float4*)(conv_w + c * 4);
    float cb = conv_b[c];
    #pragma unroll
    for (int i = 0; i < 16; i++) {
      float v = cb;
      v = fmaf(a[i + 0], cw.x, v);
      v = fmaf(a[i + 1], cw.y, v);
      v = fmaf(a[i + 2], cw.z, v);
      v = fmaf(a[i + 3], cw.w, v);
      xs[(size_t)(row0 + i) * DIN + c] = siluf(v);
    }
  } else {
    int cz = c - DIN;
    #pragma unroll
    for (int i = 0; i < 16; i++) zo[(size_t)(row0 + i) * DIN + cz] = a[i + 3];
  }
}

// ---------------- K3b: x-proj GEMM (160 outs = 128 dt + 16 B + 16 C), K=128 --------
// 320 threads: t<160 -> col=t rows 0..7 ; t>=160 -> col=t-160 rows 8..15. acc[8].
__global__ void k_xproj(const float* __restrict__ xs, const float* __restrict__ Wbt,
                        const float* __restrict__ bbig,
                        float* __restrict__ dt, float* __restrict__ Bm, float* __restrict__ Cm) {
  int row0 = blockIdx.x * 16;
  int t = threadIdx.x;
  __shared__ float xt[16 * DIN];              // 16 rows x 128
  for (int i = t; i < 16 * 32; i += 320) {    // float4 granularity
    int r = i >> 5, k4 = i & 31;
    *(float4*)(xt + r * DIN + k4 * 4) = *(const float4*)(xs + (size_t)(row0 + r) * DIN + k4 * 4);
  }
  __syncthreads();

  int c = (t < 160) ? t : t - 160;
  int rbase = (t < 160) ? 0 : 8;
  float acc[8];
  float bb = bbig[c];
  #pragma unroll
  for (int r = 0; r < 8; r++) acc[r] = bb;
  const float4* xt4 = (const float4*)(xt + rbase * DIN);
  #pragma unroll 2
  for (int k4 = 0; k4 < 32; k4++) {
    float w0 = Wbt[(k4 * 4 + 0) * 160 + c];
    float w1 = Wbt[(k4 * 4 + 1) * 160 + c];
    float w2 = Wbt[(k4 * 4 + 2) * 160 + c];
    float w3 = Wbt[(k4 * 4 + 3) * 160 + c];
    #pragma unroll
    for (int r = 0; r < 8; r++) {
      float4 v = xt4[r * 32 + k4];
      acc[r] = fmaf(w0, v.x, acc[r]);
      acc[r] = fmaf(w1, v.y, acc[r]);
      acc[r] = fmaf(w2, v.z, acc[r]);
      acc[r] = fmaf(w3, v.w, acc[r]);
    }
  }
  if (c < 128) {
    #pragma unroll
    for (int r = 0; r < 8; r++)
      dt[(size_t)(row0 + rbase + r) * DIN + c] = softplusf(acc[r]);
  } else if (c < 144) {
    #pragma unroll
    for (int r = 0; r < 8; r++)
      Bm[(size_t)(row0 + rbase + r) * 16 + (c - 128)] = acc[r];
  } else {
    #pragma unroll
    for (int r = 0; r < 8; r++)
      Cm[(size_t)(row0 + rbase + r) * 16 + (c - 144)] = acc[r];
  }
}

// ---------------- K5a: scan chunk aggregates -------------------------------
__global__ void __launch_bounds__(512) k_scanA(
    const float* __restrict__ dt, const float* __restrict__ Bmat,
    const float* __restrict__ xs, const float* __restrict__ A_log,
    float* __restrict__ Ap, float* __restrict__ Bg) {
  int chunk = blockIdx.x, b = blockIdx.y;
  int t = threadIdx.x;
  int d = t >> 2, q = t & 3;
  const float* al = A_log + d * 16 + q * 4;
  float a0 = -__expf(al[0]), a1 = -__expf(al[1]);
  float a2 = -__expf(al[2]), a3 = -__expf(al[3]);
  size_t base = (size_t)b * LSEQ + (size_t)chunk * CTL;
  const float* dtp = dt + base * DIN + d;
  const float* xsp = xs + base * DIN + d;
  const float4* bp4 = (const float4*)(Bmat + base * 16 + q * 4);
  float h0 = 0.f, h1 = 0.f, h2 = 0.f, h3 = 0.f;
  float p0 = 1.f, p1 = 1.f, p2 = 1.f, p3 = 1.f;
  #pragma unroll 4
  for (int i = 0; i < CTL; i++) {
    float dtv = dtp[(size_t)i * DIN];
    float xv  = xsp[(size_t)i * DIN];
    float4 bA = bp4[i * 4];
    float u = dtv * xv;
    float e;
    e = __expf(dtv * a0); h0 = fmaf(e, h0, u * bA.x); p0 *= e;
    e = __expf(dtv * a1); h1 = fmaf(e, h1, u * bA.y); p1 *= e;
    e = __expf(dtv * a2); h2 = fmaf(e, h2, u * bA.z); p2 *= e;
    e = __expf(dtv * a3); h3 = fmaf(e, h3, u * bA.w); p3 *= e;
  }
  size_t idx = (size_t)chunk * NCHAIN + (size_t)(b * DIN + d) * 16 + q * 4;
  *(float4*)(Ap + idx) = make_float4(p0, p1, p2, p3);
  *(float4*)(Bg + idx) = make_float4(h0, h1, h2, h3);
}

// ---------------- K5b: sequential combine across chunks ----------------
__global__ void k_scanB(const float* __restrict__ Ap, const float* __restrict__ Bg,
                        float* __restrict__ hinit) {
  int chain = blockIdx.x * 64 + threadIdx.x;   // 0..4095
  float h = 0.f;
  for (int c = 0; c < NCH; c++) {
    size_t idx = (size_t)c * NCHAIN + chain;
    hinit[idx] = h;
    h = fmaf(Ap[idx], h, Bg[idx]);
  }
}

// ---------------- K5c: re-scan with init, reduce over s, gate ----------------
__global__ void __launch_bounds__(512) k_scanC(
    const float* __restrict__ dt, const float* __restrict__ Bmat,
    const float* __restrict__ Cmat, const float* __restrict__ xs,
    const float* __restrict__ z, const float* __restrict__ A_log,
    const float* __restrict__ Dp, const float* __restrict__ hinit,
    float* __restrict__ y) {
  int chunk = blockIdx.x, b = blockIdx.y;
  int t = threadIdx.x;
  int d = t >> 2, q = t & 3;
  const float* al = A_log + d * 16 + q * 4;
  float a0 = -__expf(al[0]), a1 = -__expf(al[1]);
  float a2 = -__expf(al[2]), a3 = -__expf(al[3]);
  float dp = Dp[d];
  size_t base = (size_t)b * LSEQ + (size_t)chunk * CTL;
  const float* dtp = dt + base * DIN + d;
  const float* xsp = xs + base * DIN + d;
  const float* zp  = z  + base * DIN + d;
  float* yp        = y  + base * DIN + d;
  const float4* bp4 = (const float4*)(Bmat + base * 16 + q * 4);
  const float4* cp4 = (const float4*)(Cmat + base * 16 + q * 4);
  size_t idx = (size_t)chunk * NCHAIN + (size_t)(b * DIN + d) * 16 + q * 4;
  float4 hv = *(const float4*)(hinit + idx);
  float h0 = hv.x, h1 = hv.y, h2 = hv.z, h3 = hv.w;
  #pragma unroll 2
  for (int i = 0; i < CTL; i++) {
    float dtv = dtp[(size_t)i * DIN];
    float xv  = xsp[(size_t)i * DIN];
    float4 bA = bp4[i * 4];
    float4 cA = cp4[i * 4];
    float u = dtv * xv;
    float e, p;
    e = __expf(dtv * a0); h0 = fmaf(e, h0, u * bA.x); p  = h0 * cA.x;
    e = __expf(dtv * a1); h1 = fmaf(e, h1, u * bA.y); p  = fmaf(h1, cA.y, p);
    e = __expf(dtv * a2); h2 = fmaf(e, h2, u * bA.z); p  = fmaf(h2, cA.z, p);
    e = __expf(dtv * a3); h3 = fmaf(e, h3, u * bA.w); p  = fmaf(h3, cA.w, p);
    p += __shfl_xor(p, 1);
    p += __shfl_xor(p, 2);
    if (q == 0) {
      float zv = zp[(size_t)i * DIN];
      yp[(size_t)i * DIN] = (p + xv * dp) * siluf(zv);
    }
  }
}

// ---------------- K6: out-proj + BN + GELU + residual + clip ----------------
__global__ void k_out(const float* __restrict__ y, const float* __restrict__ Mt,
                      const float* __restrict__ bp, const float* __restrict__ bn_g,
                      const float* __restrict__ bn_bt, const float* __restrict__ bn_m,
                      const float* __restrict__ bn_v, const float* __restrict__ res,
                      float* __restrict__ out) {
  int b = blockIdx.y, l0 = blockIdx.x * 64;
  int t = threadIdx.x;
  int c = t & 63, lg = t >> 6;
  __shared__ float tile[64][65];
  float acc[16];
  float bpc = bp[c];
  #pragma unroll
  for (int i = 0; i < 16; i++) acc[i] = bpc;
  const float* yb = y + ((size_t)b * LSEQ + l0 + lg * 16) * DIN;
  #pragma unroll 4
  for (int d = 0; d < DIN; d++) {
    float m = Mt[d * 64 + c];
    #pragma unroll
    for (int i = 0; i < 16; i++) acc[i] = fmaf(m, yb[i * DIN + d], acc[i]);
  }
  float g = bn_g[c], bt = bn_bt[c], mu = bn_m[c];
  float iv = rsqrtf(bn_v[c] + 1e-5f);
  #pragma unroll
  for (int i = 0; i < 16; i++) {
    float a = (acc[i] - mu) * iv * g + bt;
    a = 0.5f * a * (1.f + erff(a * 0.70710678118654752f));   // exact GELU
    tile[c][lg * 16 + i] = a;
  }
  __syncthreads();
  int l = t & 63, cg = t >> 6;
  #pragma unroll
  for (int i = 0; i < 16; i++) {
    int cc = cg * 16 + i;
    size_t idx = ((size_t)(b * DIMC + cc)) * LSEQ + l0 + l;
    out[idx] = clip10(res[idx] + tile[cc][l]);
  }
}

extern "C" void kernel_launch(void* const* d_in, const int* in_sizes, int n_in,
                              void* d_out, int out_size, void* d_ws, size_t ws_size,
                              hipStream_t stream) {
  const float* x       = (const float*)d_in[0];
  const float* gn_g    = (const float*)d_in[1];
  const float* gn_b    = (const float*)d_in[2];
  const float* W_in    = (const float*)d_in[3];
  const float* b_in    = (const float*)d_in[4];
  const float* conv_w  = (const float*)d_in[5];
  const float* conv_b  = (const float*)d_in[6];
  const float* W_xproj = (const float*)d_in[7];
  const float* W_dt    = (const float*)d_in[8];
  const float* b_dt    = (const float*)d_in[9];
  const float* A_log   = (const float*)d_in[10];
  const float* Dp      = (const float*)d_in[11];
  const float* W_out   = (const float*)d_in[12];
  const float* b_out   = (const float*)d_in[13];
  const float* proj_w  = (const float*)d_in[14];
  const float* proj_b  = (const float*)d_in[15];
  const float* bn_g    = (const float*)d_in[16];
  const float* bn_bt   = (const float*)d_in[17];
  const float* bn_m    = (const float*)d_in[18];
  const float* bn_v    = (const float*)d_in[19];

  float* ws = (float*)d_ws;
  float* sums = ws;                               // 64
  float* seq  = ws + 64;                          // 1179648  (B,L,C); dead after k_inproj_conv
  float* res  = seq + 1179648;                    // 1179648  (B,C,L)
  float* ybuf = res + 1179648;                    // 2359296  (B,L,128)
  float* zbuf = ybuf + 2359296;                   // 2359296
  float* xsb  = zbuf + 2359296;                   // 2359296
  float* dtb  = xsb + 2359296;                    // 2359296
  float* Bmb  = dtb + 2359296;                    // 294912
  float* Cmb  = Bmb + 294912;                     // 294912
  float* Wt   = Cmb + 294912;                     // 16384
  float* Mt   = Wt + 16384;                       // 8192
  float* bp   = Mt + 8192;                        // 64
  float* Wbt  = bp + 64;                          // 20480
  float* bbig = Wbt + 20480;                      // 160
  float* Bgb  = bbig + 160;                       // 786432 (NCH*NCHAIN)
  float* hib  = Bgb + 786432;                     // 786432
  float* Apb  = seq;                              // 786432, reuses dead seq

  hipMemsetAsync(sums, 0, 64 * sizeof(float), stream);

  k_reduce<<<dim3(256, 2), 256, 0, stream>>>(x, sums);
  k_prep<<<177, 256, 0, stream>>>(W_in, proj_w, W_out, b_out, proj_b, W_xproj, W_dt, b_dt,
                                  Wt, Mt, bp, Wbt, bbig);
  k_norm<<<dim3(144, 2), 256, 0, stream>>>(x, gn_g, gn_b, sums, seq, res);
  k_inproj_conv<<<1152, 256, 0, stream>>>(seq, Wt, b_in, conv_w, conv_b, xsb, zbuf);
  k_xproj<<<1152, 320, 0, stream>>>(xsb, Wbt, bbig, dtb, Bmb, Cmb);
  k_scanA<<<dim3(NCH, 2), 512, 0, stream>>>(dtb, Bmb, xsb, A_log, Apb, Bgb);
  k_scanB<<<64, 64, 0, stream>>>(Apb, Bgb, hib);
  k_scanC<<<dim3(NCH, 2), 512, 0, stream>>>(dtb, Bmb, Cmb, xsb, zbuf, A_log, Dp, hib, ybuf);
  k_out<<<dim3(144, 2), 256, 0, stream>>>(ybuf, Mt, bp, bn_g, bn_bt, bn_m, bn_v, res,
                                          (float*)d_out);
}

// Round 6
// 267.331 us; speedup vs baseline: 2.1220x; 1.0634x over previous
//
#include <hip/hip_runtime.h>
#include <math.h>

#define DIMC 64
#define DIN  128
#define LSEQ 9216
#define NPB  (DIMC*LSEQ)      // 589824 elements per batch
#define NCH  192              // scan chunks
#define CTL  48               // chunk length: NCH*CTL == LSEQ
#define NCHAIN 4096           // 2 batches * 128 d * 16 s

__device__ __forceinline__ float siluf(float v)    { return v / (1.f + __expf(-v)); }
__device__ __forceinline__ float softplusf(float v){ return (v > 15.f) ? v : __logf(1.f + __expf(v)); }
__device__ __forceinline__ float clip10(float v)   { return fminf(10.f, fmaxf(-10.f, v)); }

// ---------------- K1: per-batch sum / sumsq ----------------
__global__ void k_reduce(const float* __restrict__ x, float* __restrict__ sums) {
  int b = blockIdx.y;
  const float* xb = x + (size_t)b * NPB;
  float s = 0.f, s2 = 0.f;
  for (int i = blockIdx.x * blockDim.x + threadIdx.x; i < NPB; i += gridDim.x * blockDim.x) {
    float v = xb[i]; s += v; s2 = fmaf(v, v, s2);
  }
  __shared__ float l1[256], l2[256];
  int t = threadIdx.x;
  l1[t] = s; l2[t] = s2; __syncthreads();
  for (int off = 128; off > 0; off >>= 1) {
    if (t < off) { l1[t] += l1[t + off]; l2[t] += l2[t + off]; }
    __syncthreads();
  }
  if (t == 0) { atomicAdd(&sums[2*b], l1[0]); atomicAdd(&sums[2*b+1], l2[0]); }
}

// ---------------- K2: normalize + clip; write res (B,C,L) and seq (B,L,C) ----------------
__global__ void k_norm(const float* __restrict__ x, const float* __restrict__ gam,
                       const float* __restrict__ bet, const float* __restrict__ sums,
                       float* __restrict__ seq, float* __restrict__ res) {
  int b = blockIdx.y, l0 = blockIdx.x * 64;
  float mean = sums[2*b] * (1.f / NPB);
  float var  = sums[2*b+1] * (1.f / NPB) - mean * mean;
  float inv  = rsqrtf(var + 1e-5f);
  __shared__ float tile[64][65];
  int t = threadIdx.x;
  int lr = t & 63, cg = t >> 6;
  #pragma unroll
  for (int i = 0; i < 16; i++) {
    int c = i * 4 + cg;
    size_t idx = ((size_t)(b * DIMC + c)) * LSEQ + l0 + lr;
    float v = x[idx];
    v = (v - mean) * inv * gam[c] + bet[c];
    v = clip10(v);
    res[idx] = v;
    tile[c][lr] = v;
  }
  __syncthreads();
  int cc = t & 63, lg = t >> 6;
  #pragma unroll
  for (int i = 0; i < 16; i++) {
    int l = i * 4 + lg;
    seq[((size_t)(b * LSEQ + l0 + l)) * DIMC + cc] = tile[cc][l];
  }
}

// ---------------- K2p: prep — transpose W_in; fold proj_w@W_out; build fused x-proj --
// Wbtd[k*128+c] = sum_r W_dt[c,r]*W_xproj[r,k]   (dt composite, bias b_dt)
// Wbc [k*32+j]  = W_xproj[4+j, k]                (j<16 -> B, j>=16 -> C)
__global__ void k_prep(const float* __restrict__ W_in, const float* __restrict__ proj_w,
                       const float* __restrict__ W_out, const float* __restrict__ b_out,
                       const float* __restrict__ proj_b, const float* __restrict__ W_xproj,
                       const float* __restrict__ W_dt,
                       float* __restrict__ Wt, float* __restrict__ Mt, float* __restrict__ bp,
                       float* __restrict__ Wbtd, float* __restrict__ Wbc) {
  int i = blockIdx.x * 256 + threadIdx.x;
  if (i < 16384) {                              // Wt[k*256+c] = W_in[c*64+k]
    int k = i >> 8, c = i & 255;
    Wt[i] = W_in[c * 64 + k];
    return;
  }
  int j = i - 16384;
  if (j < 8192) {                               // Mt[d*64+o] = sum_c proj_w[o,c]*W_out[c,d]
    int d = j >> 6, o = j & 63;
    float a = 0.f;
    for (int c = 0; c < 64; c++) a = fmaf(proj_w[o * 64 + c], W_out[c * DIN + d], a);
    Mt[j] = a;
    return;
  }
  int k2 = j - 8192;
  if (k2 < 64) {
    float a = proj_b[k2];
    for (int c = 0; c < 64; c++) a = fmaf(proj_w[k2 * 64 + c], b_out[c], a);
    bp[k2] = a;
    return;
  }
  int m = j - 8256;
  if (m < 16384) {                              // Wbtd
    int k = m >> 7, c = m & 127;
    float v = 0.f;
    #pragma unroll
    for (int r = 0; r < 4; r++) v = fmaf(W_dt[c * 4 + r], W_xproj[r * DIN + k], v);
    Wbtd[m] = v;
    return;
  }
  int m2 = m - 16384;
  if (m2 < 4096) {                              // Wbc
    int k = m2 >> 5, jj = m2 & 31;
    Wbc[m2] = W_xproj[(4 + jj) * DIN + k];
  }
}

// ---------------- K3: fused in-proj GEMM + conv + SiLU + x-proj(dt/B/C) ----------------
// 16 output rows (+3 halo recomputed). Phase 1: 256 thr = 1 col each, xz GEMM + conv.
// Phase 2a: 128 dt cols x 2 row-halves from LDS x-tile. Phase 2b: 32 B/C cols.
__global__ void __launch_bounds__(256) k_mid(
    const float* __restrict__ seq, const float* __restrict__ Wt,
    const float* __restrict__ b_in, const float* __restrict__ conv_w,
    const float* __restrict__ conv_b, const float* __restrict__ Wbtd,
    const float* __restrict__ Wbc, const float* __restrict__ b_dt,
    float* __restrict__ xs, float* __restrict__ zo, float* __restrict__ dt,
    float* __restrict__ Bm, float* __restrict__ Cm) {
  int row0 = blockIdx.x * 16;
  int l0 = row0 % LSEQ;                       // 0 only at a batch start
  int t = threadIdx.x;
  __shared__ float sq[19 * 64];               // seq rows row0-3 .. row0+15
  __shared__ float xt[16 * DIN];              // conv+silu outputs (x-tile)
  for (int i = t; i < 19 * 16; i += 256) {
    int r = i >> 4, k4 = i & 15;
    int rr = row0 - 3 + r; if (rr < 0) rr = 0;
    *(float4*)(sq + r * 64 + k4 * 4) = *(const float4*)(seq + (size_t)rr * DIMC + k4 * 4);
  }
  __syncthreads();

  {
    int c = t;
    float bi = b_in[c];
    float a[19];
    #pragma unroll
    for (int r = 0; r < 19; r++) a[r] = bi;
    const float4* sq4 = (const float4*)sq;
    #pragma unroll 4
    for (int k4 = 0; k4 < 16; k4++) {
      float w0 = Wt[(k4 * 4 + 0) * 256 + c];
      float w1 = Wt[(k4 * 4 + 1) * 256 + c];
      float w2 = Wt[(k4 * 4 + 2) * 256 + c];
      float w3 = Wt[(k4 * 4 + 3) * 256 + c];
      #pragma unroll
      for (int r = 0; r < 19; r++) {
        float4 v = sq4[r * 16 + k4];
        a[r] = fmaf(w0, v.x, a[r]);
        a[r] = fmaf(w1, v.y, a[r]);
        a[r] = fmaf(w2, v.z, a[r]);
        a[r] = fmaf(w3, v.w, a[r]);
      }
    }
    if (c < DIN) {
      if (l0 == 0) { a[0] = 0.f; a[1] = 0.f; a[2] = 0.f; }   // causal zero-pad
      float4 cw = *(const float4*)(conv_w + c * 4);
      float cb = conv_b[c];
      #pragma unroll
      for (int i = 0; i < 16; i++) {
        float v = cb;
        v = fmaf(a[i + 0], cw.x, v);
        v = fmaf(a[i + 1], cw.y, v);
        v = fmaf(a[i + 2], cw.z, v);
        v = fmaf(a[i + 3], cw.w, v);
        float sv = siluf(v);
        xs[(size_t)(row0 + i) * DIN + c] = sv;
        xt[i * DIN + c] = sv;
      }
    } else {
      int cz = c - DIN;
      #pragma unroll
      for (int i = 0; i < 16; i++) zo[(size_t)(row0 + i) * DIN + cz] = a[i + 3];
    }
  }
  __syncthreads();

  // Phase 2a: dt composite (128 cols), acc over K=128
  {
    int cd = t & 127, rb = (t >> 7) * 8;
    float acc[8];
    float bb = b_dt[cd];
    #pragma unroll
    for (int r = 0; r < 8; r++) acc[r] = bb;
    const float4* xt4 = (const float4*)(xt + rb * DIN);
    #pragma unroll 2
    for (int k4 = 0; k4 < 32; k4++) {
      float w0 = Wbtd[(k4 * 4 + 0) * 128 + cd];
      float w1 = Wbtd[(k4 * 4 + 1) * 128 + cd];
      float w2 = Wbtd[(k4 * 4 + 2) * 128 + cd];
      float w3 = Wbtd[(k4 * 4 + 3) * 128 + cd];
      #pragma unroll
      for (int r = 0; r < 8; r++) {
        float4 v = xt4[r * 32 + k4];
        acc[r] = fmaf(w0, v.x, acc[r]);
        acc[r] = fmaf(w1, v.y, acc[r]);
        acc[r] = fmaf(w2, v.z, acc[r]);
        acc[r] = fmaf(w3, v.w, acc[r]);
      }
    }
    #pragma unroll
    for (int r = 0; r < 8; r++)
      dt[(size_t)(row0 + rb + r) * DIN + cd] = softplusf(acc[r]);
  }

  // Phase 2b: B/C (32 cols), 8 row-groups x 2 rows
  {
    int cb = t & 31, rg = t >> 5;
    float a0 = 0.f, a1 = 0.f;
    const float4* x0 = (const float4*)(xt + (rg * 2 + 0) * DIN);
    const float4* x1 = (const float4*)(xt + (rg * 2 + 1) * DIN);
    #pragma unroll 2
    for (int k4 = 0; k4 < 32; k4++) {
      float w0 = Wbc[(k4 * 4 + 0) * 32 + cb];
      float w1 = Wbc[(k4 * 4 + 1) * 32 + cb];
      float w2 = Wbc[(k4 * 4 + 2) * 32 + cb];
      float w3 = Wbc[(k4 * 4 + 3) * 32 + cb];
      float4 v0 = x0[k4], v1 = x1[k4];
      a0 = fmaf(w0, v0.x, a0); a0 = fmaf(w1, v0.y, a0);
      a0 = fmaf(w2, v0.z, a0); a0 = fmaf(w3, v0.w, a0);
      a1 = fmaf(w0, v1.x, a1); a1 = fmaf(w1, v1.y, a1);
      a1 = fmaf(w2, v1.z, a1); a1 = fmaf(w3, v1.w, a1);
    }
    size_t r0 = (size_t)row0 + rg * 2;
    float* dst = (cb < 16) ? (Bm + r0 * 16 + cb) : (Cm + r0 * 16 + (cb - 16));
    dst[0]  = a0;
    dst[16] = a1;
  }
}

// ---------------- K5a: scan chunk aggregates -------------------------------
__global__ void __launch_bounds__(512) k_scanA(
    const float* __restrict__ dt, const float* __restrict__ Bmat,
    const float* __restrict__ xs, const float* __restrict__ A_log,
    float* __restrict__ Ap, float* __restrict__ Bg) {
  int chunk = blockIdx.x, b = blockIdx.y;
  int t = threadIdx.x;
  int d = t >> 2, q = t & 3;
  const float* al = A_log + d * 16 + q * 4;
  float a0 = -__expf(al[0]), a1 = -__expf(al[1]);
  float a2 = -__expf(al[2]), a3 = -__expf(al[3]);
  size_t base = (size_t)b * LSEQ + (size_t)chunk * CTL;
  const float* dtp = dt + base * DIN + d;
  const float* xsp = xs + base * DIN + d;
  const float4* bp4 = (const float4*)(Bmat + base * 16 + q * 4);
  float h0 = 0.f, h1 = 0.f, h2 = 0.f, h3 = 0.f;
  float p0 = 1.f, p1 = 1.f, p2 = 1.f, p3 = 1.f;
  #pragma unroll 4
  for (int i = 0; i < CTL; i++) {
    float dtv = dtp[(size_t)i * DIN];
    float xv  = xsp[(size_t)i * DIN];
    float4 bA = bp4[i * 4];
    float u = dtv * xv;
    float e;
    e = __expf(dtv * a0); h0 = fmaf(e, h0, u * bA.x); p0 *= e;
    e = __expf(dtv * a1); h1 = fmaf(e, h1, u * bA.y); p1 *= e;
    e = __expf(dtv * a2); h2 = fmaf(e, h2, u * bA.z); p2 *= e;
    e = __expf(dtv * a3); h3 = fmaf(e, h3, u * bA.w); p3 *= e;
  }
  size_t idx = (size_t)chunk * NCHAIN + (size_t)(b * DIN + d) * 16 + q * 4;
  *(float4*)(Ap + idx) = make_float4(p0, p1, p2, p3);
  *(float4*)(Bg + idx) = make_float4(h0, h1, h2, h3);
}

// ---------------- K5b: sequential combine across chunks ----------------
__global__ void k_scanB(const float* __restrict__ Ap, const float* __restrict__ Bg,
                        float* __restrict__ hinit) {
  int chain = blockIdx.x * 64 + threadIdx.x;   // 0..4095
  float h = 0.f;
  for (int c = 0; c < NCH; c++) {
    size_t idx = (size_t)c * NCHAIN + chain;
    hinit[idx] = h;
    h = fmaf(Ap[idx], h, Bg[idx]);
  }
}

// ---------------- K5c: re-scan with init, reduce over s, gate ----------------
__global__ void __launch_bounds__(512) k_scanC(
    const float* __restrict__ dt, const float* __restrict__ Bmat,
    const float* __restrict__ Cmat, const float* __restrict__ xs,
    const float* __restrict__ z, const float* __restrict__ A_log,
    const float* __restrict__ Dp, const float* __restrict__ hinit,
    float* __restrict__ y) {
  int chunk = blockIdx.x, b = blockIdx.y;
  int t = threadIdx.x;
  int d = t >> 2, q = t & 3;
  const float* al = A_log + d * 16 + q * 4;
  float a0 = -__expf(al[0]), a1 = -__expf(al[1]);
  float a2 = -__expf(al[2]), a3 = -__expf(al[3]);
  float dp = Dp[d];
  size_t base = (size_t)b * LSEQ + (size_t)chunk * CTL;
  const float* dtp = dt + base * DIN + d;
  const float* xsp = xs + base * DIN + d;
  const float* zp  = z  + base * DIN + d;
  float* yp        = y  + base * DIN + d;
  const float4* bp4 = (const float4*)(Bmat + base * 16 + q * 4);
  const float4* cp4 = (const float4*)(Cmat + base * 16 + q * 4);
  size_t idx = (size_t)chunk * NCHAIN + (size_t)(b * DIN + d) * 16 + q * 4;
  float4 hv = *(const float4*)(hinit + idx);
  float h0 = hv.x, h1 = hv.y, h2 = hv.z, h3 = hv.w;
  #pragma unroll 2
  for (int i = 0; i < CTL; i++) {
    float dtv = dtp[(size_t)i * DIN];
    float xv  = xsp[(size_t)i * DIN];
    float4 bA = bp4[i * 4];
    float4 cA = cp4[i * 4];
    float u = dtv * xv;
    float e, p;
    e = __expf(dtv * a0); h0 = fmaf(e, h0, u * bA.x); p  = h0 * cA.x;
    e = __expf(dtv * a1); h1 = fmaf(e, h1, u * bA.y); p  = fmaf(h1, cA.y, p);
    e = __expf(dtv * a2); h2 = fmaf(e, h2, u * bA.z); p  = fmaf(h2, cA.z, p);
    e = __expf(dtv * a3); h3 = fmaf(e, h3, u * bA.w); p  = fmaf(h3, cA.w, p);
    p += __shfl_xor(p, 1);
    p += __shfl_xor(p, 2);
    if (q == 0) {
      float zv = zp[(size_t)i * DIN];
      yp[(size_t)i * DIN] = (p + xv * dp) * siluf(zv);
    }
  }
}

// ---------------- K6: out-proj + BN + GELU + residual + clip ----------------
// 32-row tiles, float4 y loads. 256 thr: c=t&63, g=t>>6 -> 8 rows each.
__global__ void __launch_bounds__(256) k_out(
    const float* __restrict__ y, const float* __restrict__ Mt,
    const float* __restrict__ bp, const float* __restrict__ bn_g,
    const float* __restrict__ bn_bt, const float* __restrict__ bn_m,
    const float* __restrict__ bn_v, const float* __restrict__ res,
    float* __restrict__ out) {
  int b = blockIdx.y, l0 = blockIdx.x * 32;
  int t = threadIdx.x;
  int c = t & 63, g = t >> 6;
  __shared__ float tile[64 * 33];
  float acc[8];
  float bpc = bp[c];
  #pragma unroll
  for (int i = 0; i < 8; i++) acc[i] = bpc;
  const float* yb = y + ((size_t)b * LSEQ + l0 + g * 8) * DIN;
  #pragma unroll 4
  for (int d4 = 0; d4 < 32; d4++) {
    float m0 = Mt[(d4 * 4 + 0) * 64 + c];
    float m1 = Mt[(d4 * 4 + 1) * 64 + c];
    float m2 = Mt[(d4 * 4 + 2) * 64 + c];
    float m3 = Mt[(d4 * 4 + 3) * 64 + c];
    #pragma unroll
    for (int i = 0; i < 8; i++) {
      float4 v = *(const float4*)(yb + (size_t)i * DIN + d4 * 4);
      acc[i] = fmaf(m0, v.x, acc[i]);
      acc[i] = fmaf(m1, v.y, acc[i]);
      acc[i] = fmaf(m2, v.z, acc[i]);
      acc[i] = fmaf(m3, v.w, acc[i]);
    }
  }
  float gg = bn_g[c], bt = bn_bt[c], mu = bn_m[c];
  float iv = rsqrtf(bn_v[c] + 1e-5f);
  #pragma unroll
  for (int i = 0; i < 8; i++) {
    float a = (acc[i] - mu) * iv * gg + bt;
    a = 0.5f * a * (1.f + erff(a * 0.70710678118654752f));   // exact GELU
    tile[c * 33 + g * 8 + i] = a;
  }
  __syncthreads();
  int l = t & 31, cg = t >> 5;
  #pragma unroll
  for (int i = 0; i < 8; i++) {
    int cc = cg * 8 + i;
    size_t idx = ((size_t)(b * DIMC + cc)) * LSEQ + l0 + l;
    out[idx] = clip10(res[idx] + tile[cc * 33 + l]);
  }
}

extern "C" void kernel_launch(void* const* d_in, const int* in_sizes, int n_in,
                              void* d_out, int out_size, void* d_ws, size_t ws_size,
                              hipStream_t stream) {
  const float* x       = (const float*)d_in[0];
  const float* gn_g    = (const float*)d_in[1];
  const float* gn_b    = (const float*)d_in[2];
  const float* W_in    = (const float*)d_in[3];
  const float* b_in    = (const float*)d_in[4];
  const float* conv_w  = (const float*)d_in[5];
  const float* conv_b  = (const float*)d_in[6];
  const float* W_xproj = (const float*)d_in[7];
  const float* W_dt    = (const float*)d_in[8];
  const float* b_dt    = (const float*)d_in[9];
  const float* A_log   = (const float*)d_in[10];
  const float* Dp      = (const float*)d_in[11];
  const float* W_out   = (const float*)d_in[12];
  const float* b_out   = (const float*)d_in[13];
  const float* proj_w  = (const float*)d_in[14];
  const float* proj_b  = (const float*)d_in[15];
  const float* bn_g    = (const float*)d_in[16];
  const float* bn_bt   = (const float*)d_in[17];
  const float* bn_m    = (const float*)d_in[18];
  const float* bn_v    = (const float*)d_in[19];

  float* ws = (float*)d_ws;
  float* sums = ws;                               // 64
  float* seq  = ws + 64;                          // 1179648  (B,L,C); dead after k_mid
  float* res  = seq + 1179648;                    // 1179648  (B,C,L)
  float* ybuf = res + 1179648;                    // 2359296  (B,L,128)
  float* zbuf = ybuf + 2359296;                   // 2359296
  float* xsb  = zbuf + 2359296;                   // 2359296
  float* dtb  = xsb + 2359296;                    // 2359296
  float* Bmb  = dtb + 2359296;                    // 294912
  float* Cmb  = Bmb + 294912;                     // 294912
  float* Wt   = Cmb + 294912;                     // 16384
  float* Mt   = Wt + 16384;                       // 8192
  float* bp   = Mt + 8192;                        // 64
  float* Wbtd = bp + 64;                          // 16384
  float* Wbc  = Wbtd + 16384;                     // 4096
  float* Bgb  = Wbc + 4096;                       // 786432 (NCH*NCHAIN)
  float* hib  = Bgb + 786432;                     // 786432
  float* Apb  = seq;                              // 786432, reuses dead seq

  hipMemsetAsync(sums, 0, 64 * sizeof(float), stream);

  k_reduce<<<dim3(256, 2), 256, 0, stream>>>(x, sums);
  k_prep<<<177, 256, 0, stream>>>(W_in, proj_w, W_out, b_out, proj_b, W_xproj, W_dt,
                                  Wt, Mt, bp, Wbtd, Wbc);
  k_norm<<<dim3(144, 2), 256, 0, stream>>>(x, gn_g, gn_b, sums, seq, res);
  k_mid<<<1152, 256, 0, stream>>>(seq, Wt, b_in, conv_w, conv_b, Wbtd, Wbc, b_dt,
                                  xsb, zbuf, dtb, Bmb, Cmb);
  k_scanA<<<dim3(NCH, 2), 512, 0, stream>>>(dtb, Bmb, xsb, A_log, Apb, Bgb);
  k_scanB<<<64, 64, 0, stream>>>(Apb, Bgb, hib);
  k_scanC<<<dim3(NCH, 2), 512, 0, stream>>>(dtb, Bmb, Cmb, xsb, zbuf, A_log, Dp, hib, ybuf);
  k_out<<<dim3(288, 2), 256, 0, stream>>>(ybuf, Mt, bp, bn_g, bn_bt, bn_m, bn_v, res,
                                          (float*)d_out);
}

// Round 7
// 248.723 us; speedup vs baseline: 2.2808x; 1.0748x over previous
//
#include <hip/hip_runtime.h>
#include <math.h>

#define DIMC 64
#define DIN  128
#define LSEQ 9216
#define NPB  (DIMC*LSEQ)      // 589824 elements per batch
#define NCH  192              // scan chunks
#define CTL  48               // chunk length: NCH*CTL == LSEQ
#define NCHAIN 4096           // 2 batches * 128 d * 16 s

__device__ __forceinline__ float siluf(float v)    { return v / (1.f + __expf(-v)); }
__device__ __forceinline__ float softplusf(float v){ return (v > 15.f) ? v : __logf(1.f + __expf(v)); }
__device__ __forceinline__ float clip10(float v)   { return fminf(10.f, fmaxf(-10.f, v)); }
__device__ __forceinline__ float getc(const float4 v, int k) {
  return (k == 0) ? v.x : (k == 1) ? v.y : (k == 2) ? v.z : v.w;
}

// ---------------- K1: per-batch sum/sumsq (blocks x<256) + weight prep (x>=256,y==0) ---
__global__ void k_init(const float* __restrict__ x, float* __restrict__ sums,
                       const float* __restrict__ W_in, const float* __restrict__ proj_w,
                       const float* __restrict__ W_out, const float* __restrict__ b_out,
                       const float* __restrict__ proj_b, const float* __restrict__ W_xproj,
                       const float* __restrict__ W_dt,
                       float* __restrict__ Wtp, float* __restrict__ Mtp, float* __restrict__ bp,
                       float* __restrict__ Wbtd2, float* __restrict__ Wbc) {
  int bx = blockIdx.x, by = blockIdx.y;
  int t = threadIdx.x;
  if (bx < 256) {
    const float* xb = x + (size_t)by * NPB;
    float s = 0.f, s2 = 0.f;
    for (int i = bx * 256 + t; i < NPB; i += 65536) {
      float v = xb[i]; s += v; s2 = fmaf(v, v, s2);
    }
    __shared__ float l1[256], l2[256];
    l1[t] = s; l2[t] = s2; __syncthreads();
    for (int off = 128; off > 0; off >>= 1) {
      if (t < off) { l1[t] += l1[t + off]; l2[t] += l2[t + off]; }
      __syncthreads();
    }
    if (t == 0) { atomicAdd(&sums[2*by], l1[0]); atomicAdd(&sums[2*by+1], l2[0]); }
    return;
  }
  if (by != 0) return;
  int i = (bx - 256) * 256 + t;
  if (i < 16384) {                       // Wtp[(k*128+c)*2+h] = W_in[(c+128h)*64+k]
    int k = i >> 8, cc = i & 255, c = cc & 127, h = cc >> 7;
    Wtp[(k * 128 + c) * 2 + h] = W_in[(c + 128 * h) * 64 + k];
    return;
  }
  int j = i - 16384;
  if (j < 8192) {                        // Mtp[(d*32+o32)*2+h] = (proj_w@W_out)[o][d]
    int d = j >> 6, o = j & 63, o32 = o & 31, h = o >> 5;
    float a = 0.f;
    for (int c = 0; c < 64; c++) a = fmaf(proj_w[o * 64 + c], W_out[c * DIN + d], a);
    Mtp[(d * 32 + o32) * 2 + h] = a;
    return;
  }
  int k2 = j - 8192;
  if (k2 < 64) {
    float a = proj_b[k2];
    for (int c = 0; c < 64; c++) a = fmaf(proj_w[k2 * 64 + c], b_out[c], a);
    bp[k2] = a;
    return;
  }
  int m = j - 8256;
  if (m < 16384) {                       // Wbtd2[(k*64+c)*2+h] = (W_dt@W_xproj[:4])[c+64h][k]
    int k = m >> 7, cc = m & 127, c = cc & 63, h = cc >> 6;
    float v = 0.f;
    #pragma unroll
    for (int r = 0; r < 4; r++) v = fmaf(W_dt[(c + 64 * h) * 4 + r], W_xproj[r * DIN + k], v);
    Wbtd2[(k * 64 + c) * 2 + h] = v;
    return;
  }
  int m2 = m - 16384;
  if (m2 < 4096) {                       // Wbc[k*32+j] = W_xproj[4+j][k]
    int k = m2 >> 5, jj = m2 & 31;
    Wbc[m2] = W_xproj[(4 + jj) * DIN + k];
  }
}

// ---------------- K2: normalize + clip; write res (B,C,L) and seq (B,L,C) ----------------
__global__ void k_norm(const float* __restrict__ x, const float* __restrict__ gam,
                       const float* __restrict__ bet, const float* __restrict__ sums,
                       float* __restrict__ seq, float* __restrict__ res) {
  int b = blockIdx.y, l0 = blockIdx.x * 64;
  float mean = sums[2*b] * (1.f / NPB);
  float var  = sums[2*b+1] * (1.f / NPB) - mean * mean;
  float inv  = rsqrtf(var + 1e-5f);
  __shared__ float tile[64][65];
  int t = threadIdx.x;
  int lr = t & 63, cg = t >> 6;
  #pragma unroll
  for (int i = 0; i < 16; i++) {
    int c = i * 4 + cg;
    size_t idx = ((size_t)(b * DIMC + c)) * LSEQ + l0 + lr;
    float v = x[idx];
    v = (v - mean) * inv * gam[c] + bet[c];
    v = clip10(v);
    res[idx] = v;
    tile[c][lr] = v;
  }
  __syncthreads();
  int cc = t & 63, lg = t >> 6;
  #pragma unroll
  for (int i = 0; i < 16; i++) {
    int l = i * 4 + lg;
    seq[((size_t)(b * LSEQ + l0 + l)) * DIMC + cc] = tile[cc][l];
  }
}

// ---------------- K3: fused in-proj GEMM + conv + SiLU + x-proj(dt/B/C) ----------------
// Phase 1: col-pair (c, c+128), 2 row-halves (11-row windows); seq read via
// wave-uniform scalar loads (no LDS). Phase 2: xt LDS tile, wave-broadcast reads.
__global__ void __launch_bounds__(256) k_mid(
    const float* __restrict__ seq, const float* __restrict__ Wtp,
    const float* __restrict__ b_in, const float* __restrict__ conv_w,
    const float* __restrict__ conv_b, const float* __restrict__ Wbtd2,
    const float* __restrict__ Wbc, const float* __restrict__ b_dt,
    float* __restrict__ xs, float* __restrict__ zo, float* __restrict__ dt,
    float* __restrict__ Bm, float* __restrict__ Cm) {
  int row0 = blockIdx.x * 16;
  int t = threadIdx.x;
  __shared__ float xt[16 * DIN];

  // ---- Phase 1: in-proj + conv + silu ----
  {
    int c = t & 127;
    int rh = __builtin_amdgcn_readfirstlane(t >> 7);   // wave-uniform row-half
    long base = (long)row0 - 3 + rh * 8;               // pre-conv window start
    float bx_ = b_in[c], bz_ = b_in[c + 128];
    float ax[11], az[11];
    #pragma unroll
    for (int j2 = 0; j2 < 11; j2++) { ax[j2] = bx_; az[j2] = bz_; }
    const float4* sqg = (const float4*)seq;
    const float2* W2  = (const float2*)Wtp;
    for (int k4 = 0; k4 < 16; k4++) {
      float4 sv[11];
      #pragma unroll
      for (int j2 = 0; j2 < 11; j2++) {
        long rr = base + j2; if (rr < 0) rr = 0;       // uniform clamp
        sv[j2] = sqg[(size_t)rr * 16 + k4];
      }
      #pragma unroll
      for (int kk = 0; kk < 4; kk++) {
        float2 w = W2[(size_t)(k4 * 4 + kk) * 128 + c];
        #pragma unroll
        for (int j2 = 0; j2 < 11; j2++) {
          float svv = getc(sv[j2], kk);
          ax[j2] = fmaf(w.x, svv, ax[j2]);
          az[j2] = fmaf(w.y, svv, az[j2]);
        }
      }
    }
    if ((row0 % LSEQ) == 0 && rh == 0) { ax[0] = 0.f; ax[1] = 0.f; ax[2] = 0.f; }
    float4 cw = *(const float4*)(conv_w + c * 4);
    float cb = conv_b[c];
    #pragma unroll
    for (int i2 = 0; i2 < 8; i2++) {
      float v = cb;
      v = fmaf(ax[i2 + 0], cw.x, v);
      v = fmaf(ax[i2 + 1], cw.y, v);
      v = fmaf(ax[i2 + 2], cw.z, v);
      v = fmaf(ax[i2 + 3], cw.w, v);
      float sv_ = siluf(v);
      int r = rh * 8 + i2;
      xs[(size_t)(row0 + r) * DIN + c] = sv_;
      xt[r * DIN + c] = sv_;
      zo[(size_t)(row0 + r) * DIN + c] = az[i2 + 3];
    }
  }
  __syncthreads();

  const float4* xt4 = (const float4*)xt;

  // ---- Phase 2a: dt composite, col-pair (cd, cd+64), 4 rows each ----
  {
    int cd = t & 63, rg = t >> 6;
    float acc0[4], acc1[4];
    float bd0 = b_dt[cd], bd1 = b_dt[cd + 64];
    #pragma unroll
    for (int r = 0; r < 4; r++) { acc0[r] = bd0; acc1[r] = bd1; }
    const float2* Wd2 = (const float2*)Wbtd2;
    for (int k4 = 0; k4 < 32; k4++) {
      float4 v0 = xt4[(rg * 4 + 0) * 32 + k4];
      float4 v1 = xt4[(rg * 4 + 1) * 32 + k4];
      float4 v2 = xt4[(rg * 4 + 2) * 32 + k4];
      float4 v3 = xt4[(rg * 4 + 3) * 32 + k4];
      #pragma unroll
      for (int kk = 0; kk < 4; kk++) {
        float2 w = Wd2[(size_t)(k4 * 4 + kk) * 64 + cd];
        float s0 = getc(v0, kk), s1 = getc(v1, kk), s2 = getc(v2, kk), s3 = getc(v3, kk);
        acc0[0] = fmaf(w.x, s0, acc0[0]); acc1[0] = fmaf(w.y, s0, acc1[0]);
        acc0[1] = fmaf(w.x, s1, acc0[1]); acc1[1] = fmaf(w.y, s1, acc1[1]);
        acc0[2] = fmaf(w.x, s2, acc0[2]); acc1[2] = fmaf(w.y, s2, acc1[2]);
        acc0[3] = fmaf(w.x, s3, acc0[3]); acc1[3] = fmaf(w.y, s3, acc1[3]);
      }
    }
    #pragma unroll
    for (int r = 0; r < 4; r++) {
      size_t ro = (size_t)(row0 + rg * 4 + r) * DIN;
      dt[ro + cd]      = softplusf(acc0[r]);
      dt[ro + cd + 64] = softplusf(acc1[r]);
    }
  }

  // ---- Phase 2b: B/C (32 cols), 2 rows each ----
  {
    int cb2 = t & 31, rg = t >> 5;
    float a0 = 0.f, a1 = 0.f;
    for (int k4 = 0; k4 < 32; k4++) {
      float4 v0 = xt4[(rg * 2 + 0) * 32 + k4];
      float4 v1 = xt4[(rg * 2 + 1) * 32 + k4];
      #pragma unroll
      for (int kk = 0; kk < 4; kk++) {
        float w = Wbc[(k4 * 4 + kk) * 32 + cb2];
        a0 = fmaf(w, getc(v0, kk), a0);
        a1 = fmaf(w, getc(v1, kk), a1);
      }
    }
    size_t r0 = (size_t)row0 + rg * 2;
    float* dst = (cb2 < 16) ? (Bm + r0 * 16 + cb2) : (Cm + r0 * 16 + (cb2 - 16));
    dst[0]  = a0;
    dst[16] = a1;
  }
}

// ---------------- K5a: scan chunk aggregates -------------------------------
__global__ void __launch_bounds__(512) k_scanA(
    const float* __restrict__ dt, const float* __restrict__ Bmat,
    const float* __restrict__ xs, const float* __restrict__ A_log,
    float* __restrict__ Ap, float* __restrict__ Bg) {
  int chunk = blockIdx.x, b = blockIdx.y;
  int t = threadIdx.x;
  int d = t >> 2, q = t & 3;
  const float* al = A_log + d * 16 + q * 4;
  float a0 = -__expf(al[0]), a1 = -__expf(al[1]);
  float a2 = -__expf(al[2]), a3 = -__expf(al[3]);
  size_t base = (size_t)b * LSEQ + (size_t)chunk * CTL;
  const float* dtp = dt + base * DIN + d;
  const float* xsp = xs + base * DIN + d;
  const float4* bp4 = (const float4*)(Bmat + base * 16 + q * 4);
  float h0 = 0.f, h1 = 0.f, h2 = 0.f, h3 = 0.f;
  float p0 = 1.f, p1 = 1.f, p2 = 1.f, p3 = 1.f;
  #pragma unroll 4
  for (int i = 0; i < CTL; i++) {
    float dtv = dtp[(size_t)i * DIN];
    float xv  = xsp[(size_t)i * DIN];
    float4 bA = bp4[i * 4];
    float u = dtv * xv;
    float e;
    e = __expf(dtv * a0); h0 = fmaf(e, h0, u * bA.x); p0 *= e;
    e = __expf(dtv * a1); h1 = fmaf(e, h1, u * bA.y); p1 *= e;
    e = __expf(dtv * a2); h2 = fmaf(e, h2, u * bA.z); p2 *= e;
    e = __expf(dtv * a3); h3 = fmaf(e, h3, u * bA.w); p3 *= e;
  }
  size_t idx = (size_t)chunk * NCHAIN + (size_t)(b * DIN + d) * 16 + q * 4;
  *(float4*)(Ap + idx) = make_float4(p0, p1, p2, p3);
  *(float4*)(Bg + idx) = make_float4(h0, h1, h2, h3);
}

// ---------------- K5b: sequential combine across chunks ----------------
__global__ void k_scanB(const float* __restrict__ Ap, const float* __restrict__ Bg,
                        float* __restrict__ hinit) {
  int chain = blockIdx.x * 64 + threadIdx.x;   // 0..4095
  float h = 0.f;
  for (int c = 0; c < NCH; c++) {
    size_t idx = (size_t)c * NCHAIN + chain;
    hinit[idx] = h;
    h = fmaf(Ap[idx], h, Bg[idx]);
  }
}

// ---------------- K5c: re-scan + gate, then fused out-proj+BN+GELU+res+clip ------
__global__ void __launch_bounds__(512) k_scanC(
    const float* __restrict__ dt, const float* __restrict__ Bmat,
    const float* __restrict__ Cmat, const float* __restrict__ xs,
    const float* __restrict__ z, const float* __restrict__ A_log,
    const float* __restrict__ Dp, const float* __restrict__ hinit,
    const float* __restrict__ Mtp, const float* __restrict__ bp,
    const float* __restrict__ bn_g, const float* __restrict__ bn_bt,
    const float* __restrict__ bn_m, const float* __restrict__ bn_v,
    const float* __restrict__ res, float* __restrict__ out) {
  int chunk = blockIdx.x, b = blockIdx.y;
  int t = threadIdx.x;
  __shared__ float ytile[CTL * DIN];         // 24.6 KB
  __shared__ float trans[64 * 52];           // 13.3 KB
  {
    int d = t >> 2, q = t & 3;
    const float* al = A_log + d * 16 + q * 4;
    float a0 = -__expf(al[0]), a1 = -__expf(al[1]);
    float a2 = -__expf(al[2]), a3 = -__expf(al[3]);
    float dp = Dp[d];
    size_t base = (size_t)b * LSEQ + (size_t)chunk * CTL;
    const float* dtp = dt + base * DIN + d;
    const float* xsp = xs + base * DIN + d;
    const float* zp  = z  + base * DIN + d;
    const float4* bp4 = (const float4*)(Bmat + base * 16 + q * 4);
    const float4* cp4 = (const float4*)(Cmat + base * 16 + q * 4);
    size_t idx = (size_t)chunk * NCHAIN + (size_t)(b * DIN + d) * 16 + q * 4;
    float4 hv = *(const float4*)(hinit + idx);
    float h0 = hv.x, h1 = hv.y, h2 = hv.z, h3 = hv.w;
    #pragma unroll 2
    for (int i = 0; i < CTL; i++) {
      float dtv = dtp[(size_t)i * DIN];
      float xv  = xsp[(size_t)i * DIN];
      float4 bA = bp4[i * 4];
      float4 cA = cp4[i * 4];
      float u = dtv * xv;
      float e, p;
      e = __expf(dtv * a0); h0 = fmaf(e, h0, u * bA.x); p = h0 * cA.x;
      e = __expf(dtv * a1); h1 = fmaf(e, h1, u * bA.y); p = fmaf(h1, cA.y, p);
      e = __expf(dtv * a2); h2 = fmaf(e, h2, u * bA.z); p = fmaf(h2, cA.z, p);
      e = __expf(dtv * a3); h3 = fmaf(e, h3, u * bA.w); p = fmaf(h3, cA.w, p);
      p += __shfl_xor(p, 1);
      p += __shfl_xor(p, 2);
      if (q == 0) {
        float zv = zp[(size_t)i * DIN];
        ytile[i * DIN + d] = (p + xv * dp) * siluf(zv);
      }
    }
  }
  __syncthreads();

  // GEMM 48x128 @ Mtp -> 48x64, BN + GELU
  {
    int op = t & 31, rg = t >> 5;             // rg 0..15, 3 rows each
    float acc0[3], acc1[3];
    float b0 = bp[op], b1 = bp[op + 32];
    #pragma unroll
    for (int r = 0; r < 3; r++) { acc0[r] = b0; acc1[r] = b1; }
    const float4* yt4 = (const float4*)ytile;
    const float2* M2  = (const float2*)Mtp;
    for (int k4 = 0; k4 < 32; k4++) {
      float4 v0 = yt4[(rg * 3 + 0) * 32 + k4];
      float4 v1 = yt4[(rg * 3 + 1) * 32 + k4];
      float4 v2 = yt4[(rg * 3 + 2) * 32 + k4];
      #pragma unroll
      for (int kk = 0; kk < 4; kk++) {
        float2 w = M2[(size_t)(k4 * 4 + kk) * 32 + op];
        float s0 = getc(v0, kk), s1 = getc(v1, kk), s2 = getc(v2, kk);
        acc0[0] = fmaf(w.x, s0, acc0[0]); acc1[0] = fmaf(w.y, s0, acc1[0]);
        acc0[1] = fmaf(w.x, s1, acc0[1]); acc1[1] = fmaf(w.y, s1, acc1[1]);
        acc0[2] = fmaf(w.x, s2, acc0[2]); acc1[2] = fmaf(w.y, s2, acc1[2]);
      }
    }
    float g0 = bn_g[op], bt0 = bn_bt[op], mu0 = bn_m[op];
    float iv0 = rsqrtf(bn_v[op] + 1e-5f);
    float g1 = bn_g[op + 32], bt1 = bn_bt[op + 32], mu1 = bn_m[op + 32];
    float iv1 = rsqrtf(bn_v[op + 32] + 1e-5f);
    __syncthreads();          // ytile reads done before trans overwrites nothing (separate buf) — ordering for safety
    #pragma unroll
    for (int r = 0; r < 3; r++) {
      int row = rg * 3 + r;
      float a = (acc0[r] - mu0) * iv0 * g0 + bt0;
      a = 0.5f * a * (1.f + erff(a * 0.70710678118654752f));
      trans[op * 52 + row] = a;
      float a2 = (acc1[r] - mu1) * iv1 * g1 + bt1;
      a2 = 0.5f * a2 * (1.f + erff(a2 * 0.70710678118654752f));
      trans[(op + 32) * 52 + row] = a2;
    }
  }
  __syncthreads();

  // coalesced store: out[(b*64+c)*LSEQ + chunk*48 + l] with residual+clip
  int l0c = chunk * CTL;
  for (int task = t; task < 768; task += 512) {   // 64 c * 12 f4
    int c = task / 12, f = task - c * 12;
    float4 vv = *(const float4*)(trans + c * 52 + f * 4);
    size_t gi = ((size_t)(b * DIMC + c)) * LSEQ + l0c + f * 4;
    const float4 rv = *(const float4*)(res + gi);
    float4 o;
    o.x = clip10(rv.x + vv.x);
    o.y = clip10(rv.y + vv.y);
    o.z = clip10(rv.z + vv.z);
    o.w = clip10(rv.w + vv.w);
    *(float4*)(out + gi) = o;
  }
}

extern "C" void kernel_launch(void* const* d_in, const int* in_sizes, int n_in,
                              void* d_out, int out_size, void* d_ws, size_t ws_size,
                              hipStream_t stream) {
  const float* x       = (const float*)d_in[0];
  const float* gn_g    = (const float*)d_in[1];
  const float* gn_b    = (const float*)d_in[2];
  const float* W_in    = (const float*)d_in[3];
  const float* b_in    = (const float*)d_in[4];
  const float* conv_w  = (const float*)d_in[5];
  const float* conv_b  = (const float*)d_in[6];
  const float* W_xproj = (const float*)d_in[7];
  const float* W_dt    = (const float*)d_in[8];
  const float* b_dt    = (const float*)d_in[9];
  const float* A_log   = (const float*)d_in[10];
  const float* Dp      = (const float*)d_in[11];
  const float* W_out   = (const float*)d_in[12];
  const float* b_out   = (const float*)d_in[13];
  const float* proj_w  = (const float*)d_in[14];
  const float* proj_b  = (const float*)d_in[15];
  const float* bn_g    = (const float*)d_in[16];
  const float* bn_bt   = (const float*)d_in[17];
  const float* bn_m    = (const float*)d_in[18];
  const float* bn_v    = (const float*)d_in[19];

  float* ws = (float*)d_ws;
  float* sums = ws;                               // 64
  float* seq  = ws + 64;                          // 1179648 (B,L,C); dead after k_mid
  float* res  = seq + 1179648;                    // 1179648 (B,C,L)
  float* zbuf = res + 1179648;                    // 2359296
  float* xsb  = zbuf + 2359296;                   // 2359296
  float* dtb  = xsb + 2359296;                    // 2359296
  float* Bmb  = dtb + 2359296;                    // 294912
  float* Cmb  = Bmb + 294912;                     // 294912
  float* Wtp  = Cmb + 294912;                     // 16384
  float* Mtp  = Wtp + 16384;                      // 8192
  float* bp   = Mtp + 8192;                       // 64
  float* Wbtd2= bp + 64;                          // 16384
  float* Wbc  = Wbtd2 + 16384;                    // 4096
  float* Bgb  = Wbc + 4096;                       // 786432 (NCH*NCHAIN)
  float* hib  = Bgb + 786432;                     // 786432
  float* Apb  = seq;                              // 786432, reuses dead seq

  hipMemsetAsync(sums, 0, 64 * sizeof(float), stream);

  k_init<<<dim3(433, 2), 256, 0, stream>>>(x, sums, W_in, proj_w, W_out, b_out, proj_b,
                                           W_xproj, W_dt, Wtp, Mtp, bp, Wbtd2, Wbc);
  k_norm<<<dim3(144, 2), 256, 0, stream>>>(x, gn_g, gn_b, sums, seq, res);
  k_mid<<<1152, 256, 0, stream>>>(seq, Wtp, b_in, conv_w, conv_b, Wbtd2, Wbc, b_dt,
                                  xsb, zbuf, dtb, Bmb, Cmb);
  k_scanA<<<dim3(NCH, 2), 512, 0, stream>>>(dtb, Bmb, xsb, A_log, Apb, Bgb);
  k_scanB<<<64, 64, 0, stream>>>(Apb, Bgb, hib);
  k_scanC<<<dim3(NCH, 2), 512, 0, stream>>>(dtb, Bmb, Cmb, xsb, zbuf, A_log, Dp, hib,
                                            Mtp, bp, bn_g, bn_bt, bn_m, bn_v, res,
                                            (float*)d_out);
}

// Round 8
// 244.274 us; speedup vs baseline: 2.3223x; 1.0182x over previous
//
#include <hip/hip_runtime.h>
#include <math.h>

#define DIMC 64
#define DIN  128
#define LSEQ 9216
#define NPB  (DIMC*LSEQ)      // 589824 elements per batch
#define NCH  192              // scan chunks
#define CTL  48               // chunk length: NCH*CTL == LSEQ
#define NCHAIN 4096           // 2 batches * 128 d * 16 s

__device__ __forceinline__ float siluf(float v)    { return v / (1.f + __expf(-v)); }
__device__ __forceinline__ float softplusf(float v){ return (v > 15.f) ? v : __logf(1.f + __expf(v)); }
__device__ __forceinline__ float clip10(float v)   { return fminf(10.f, fmaxf(-10.f, v)); }
__device__ __forceinline__ float getc(const float4 v, int k) {
  return (k == 0) ? v.x : (k == 1) ? v.y : (k == 2) ? v.z : v.w;
}

// ---------------- K1: per-batch sum/sumsq (blocks x<256) + weight prep (x>=256,y==0) ---
__global__ void k_init(const float* __restrict__ x, float* __restrict__ sums,
                       const float* __restrict__ W_in, const float* __restrict__ proj_w,
                       const float* __restrict__ W_out, const float* __restrict__ b_out,
                       const float* __restrict__ proj_b, const float* __restrict__ W_xproj,
                       const float* __restrict__ W_dt,
                       float* __restrict__ Wtp, float* __restrict__ Mtp, float* __restrict__ bp,
                       float* __restrict__ Wbtd2, float* __restrict__ Wbc) {
  int bx = blockIdx.x, by = blockIdx.y;
  int t = threadIdx.x;
  if (bx < 256) {
    const float* xb = x + (size_t)by * NPB;
    float s = 0.f, s2 = 0.f;
    for (int i = bx * 256 + t; i < NPB; i += 65536) {
      float v = xb[i]; s += v; s2 = fmaf(v, v, s2);
    }
    __shared__ float l1[256], l2[256];
    l1[t] = s; l2[t] = s2; __syncthreads();
    for (int off = 128; off > 0; off >>= 1) {
      if (t < off) { l1[t] += l1[t + off]; l2[t] += l2[t + off]; }
      __syncthreads();
    }
    if (t == 0) { atomicAdd(&sums[2*by], l1[0]); atomicAdd(&sums[2*by+1], l2[0]); }
    return;
  }
  if (by != 0) return;
  int i = (bx - 256) * 256 + t;
  if (i < 16384) {                       // Wtp[(k*128+c)*2+h] = W_in[(c+128h)*64+k]
    int k = i >> 8, cc = i & 255, c = cc & 127, h = cc >> 7;
    Wtp[(k * 128 + c) * 2 + h] = W_in[(c + 128 * h) * 64 + k];
    return;
  }
  int j = i - 16384;
  if (j < 8192) {                        // Mtp[(d*32+o32)*2+h] = (proj_w@W_out)[o][d]
    int d = j >> 6, o = j & 63, o32 = o & 31, h = o >> 5;
    float a = 0.f;
    for (int c = 0; c < 64; c++) a = fmaf(proj_w[o * 64 + c], W_out[c * DIN + d], a);
    Mtp[(d * 32 + o32) * 2 + h] = a;
    return;
  }
  int k2 = j - 8192;
  if (k2 < 64) {
    float a = proj_b[k2];
    for (int c = 0; c < 64; c++) a = fmaf(proj_w[k2 * 64 + c], b_out[c], a);
    bp[k2] = a;
    return;
  }
  int m = j - 8256;
  if (m < 16384) {                       // Wbtd2[(k*64+c)*2+h] = (W_dt@W_xproj[:4])[c+64h][k]
    int k = m >> 7, cc = m & 127, c = cc & 63, h = cc >> 6;
    float v = 0.f;
    #pragma unroll
    for (int r = 0; r < 4; r++) v = fmaf(W_dt[(c + 64 * h) * 4 + r], W_xproj[r * DIN + k], v);
    Wbtd2[(k * 64 + c) * 2 + h] = v;
    return;
  }
  int m2 = m - 16384;
  if (m2 < 4096) {                       // Wbc[k*32+j] = W_xproj[4+j][k]
    int k = m2 >> 5, jj = m2 & 31;
    Wbc[m2] = W_xproj[(4 + jj) * DIN + k];
  }
}

// ---------------- K2: normalize + clip; write res (B,C,L) and seq (B,L,C) ----------------
__global__ void k_norm(const float* __restrict__ x, const float* __restrict__ gam,
                       const float* __restrict__ bet, const float* __restrict__ sums,
                       float* __restrict__ seq, float* __restrict__ res) {
  int b = blockIdx.y, l0 = blockIdx.x * 64;
  float mean = sums[2*b] * (1.f / NPB);
  float var  = sums[2*b+1] * (1.f / NPB) - mean * mean;
  float inv  = rsqrtf(var + 1e-5f);
  __shared__ float tile[64][65];
  int t = threadIdx.x;
  int lr = t & 63, cg = t >> 6;
  #pragma unroll
  for (int i = 0; i < 16; i++) {
    int c = i * 4 + cg;
    size_t idx = ((size_t)(b * DIMC + c)) * LSEQ + l0 + lr;
    float v = x[idx];
    v = (v - mean) * inv * gam[c] + bet[c];
    v = clip10(v);
    res[idx] = v;
    tile[c][lr] = v;
  }
  __syncthreads();
  int cc = t & 63, lg = t >> 6;
  #pragma unroll
  for (int i = 0; i < 16; i++) {
    int l = i * 4 + lg;
    seq[((size_t)(b * LSEQ + l0 + l)) * DIMC + cc] = tile[cc][l];
  }
}

// ---------------- K3: fused in-proj GEMM + conv + SiLU + x-proj(dt/B/C) ----------------
// Phase 1: LDS-staged seq tile; 128 col-pairs (c, c+128) x 2 row-halves (11-row window).
// Per wave per k4: 11 ds_read_b128 broadcast -> 88 FMA (VALU-bound).
// Phase 2: xt LDS tile, wave-broadcast reads, col-pair weights.
__global__ void __launch_bounds__(256) k_mid(
    const float* __restrict__ seq, const float* __restrict__ Wtp,
    const float* __restrict__ b_in, const float* __restrict__ conv_w,
    const float* __restrict__ conv_b, const float* __restrict__ Wbtd2,
    const float* __restrict__ Wbc, const float* __restrict__ b_dt,
    float* __restrict__ xs, float* __restrict__ zo, float* __restrict__ dt,
    float* __restrict__ Bm, float* __restrict__ Cm) {
  int row0 = blockIdx.x * 16;
  int t = threadIdx.x;
  __shared__ float sq[19 * 64];               // seq rows row0-3 .. row0+15
  __shared__ float xt[16 * DIN];              // conv+silu outputs (x-tile)

  for (int i = t; i < 19 * 16; i += 256) {
    int r = i >> 4, k4 = i & 15;
    int rr = row0 - 3 + r; if (rr < 0) rr = 0;
    *(float4*)(sq + r * 64 + k4 * 4) = *(const float4*)(seq + (size_t)rr * DIMC + k4 * 4);
  }
  __syncthreads();

  // ---- Phase 1: in-proj + conv + silu (col-pair) ----
  {
    int c = t & 127;
    int rh = t >> 7;                          // wave-uniform row-half (0/1)
    float bx_ = b_in[c], bz_ = b_in[c + 128];
    float ax[11], az[11];
    #pragma unroll
    for (int j = 0; j < 11; j++) { ax[j] = bx_; az[j] = bz_; }
    const float4* sq4 = (const float4*)sq;
    const float2* W2  = (const float2*)Wtp;
    for (int k4 = 0; k4 < 16; k4++) {
      float2 w0 = W2[(size_t)(k4 * 4 + 0) * 128 + c];
      float2 w1 = W2[(size_t)(k4 * 4 + 1) * 128 + c];
      float2 w2 = W2[(size_t)(k4 * 4 + 2) * 128 + c];
      float2 w3 = W2[(size_t)(k4 * 4 + 3) * 128 + c];
      #pragma unroll
      for (int j = 0; j < 11; j++) {
        float4 sv = sq4[(rh * 8 + j) * 16 + k4];
        ax[j] = fmaf(w0.x, sv.x, ax[j]); az[j] = fmaf(w0.y, sv.x, az[j]);
        ax[j] = fmaf(w1.x, sv.y, ax[j]); az[j] = fmaf(w1.y, sv.y, az[j]);
        ax[j] = fmaf(w2.x, sv.z, ax[j]); az[j] = fmaf(w2.y, sv.z, az[j]);
        ax[j] = fmaf(w3.x, sv.w, ax[j]); az[j] = fmaf(w3.y, sv.w, az[j]);
      }
    }
    if ((row0 % LSEQ) == 0 && rh == 0) { ax[0] = 0.f; ax[1] = 0.f; ax[2] = 0.f; }
    float4 cw = *(const float4*)(conv_w + c * 4);
    float cb = conv_b[c];
    #pragma unroll
    for (int i2 = 0; i2 < 8; i2++) {
      float v = cb;
      v = fmaf(ax[i2 + 0], cw.x, v);
      v = fmaf(ax[i2 + 1], cw.y, v);
      v = fmaf(ax[i2 + 2], cw.z, v);
      v = fmaf(ax[i2 + 3], cw.w, v);
      float sv_ = siluf(v);
      int r = rh * 8 + i2;
      xs[(size_t)(row0 + r) * DIN + c] = sv_;
      xt[r * DIN + c] = sv_;
      zo[(size_t)(row0 + r) * DIN + c] = az[i2 + 3];
    }
  }
  __syncthreads();

  const float4* xt4 = (const float4*)xt;

  // ---- Phase 2a: dt composite, col-pair (cd, cd+64), 4 rows each ----
  {
    int cd = t & 63, rg = t >> 6;
    float acc0[4], acc1[4];
    float bd0 = b_dt[cd], bd1 = b_dt[cd + 64];
    #pragma unroll
    for (int r = 0; r < 4; r++) { acc0[r] = bd0; acc1[r] = bd1; }
    const float2* Wd2 = (const float2*)Wbtd2;
    for (int k4 = 0; k4 < 32; k4++) {
      float4 v0 = xt4[(rg * 4 + 0) * 32 + k4];
      float4 v1 = xt4[(rg * 4 + 1) * 32 + k4];
      float4 v2 = xt4[(rg * 4 + 2) * 32 + k4];
      float4 v3 = xt4[(rg * 4 + 3) * 32 + k4];
      #pragma unroll
      for (int kk = 0; kk < 4; kk++) {
        float2 w = Wd2[(size_t)(k4 * 4 + kk) * 64 + cd];
        float s0 = getc(v0, kk), s1 = getc(v1, kk), s2 = getc(v2, kk), s3 = getc(v3, kk);
        acc0[0] = fmaf(w.x, s0, acc0[0]); acc1[0] = fmaf(w.y, s0, acc1[0]);
        acc0[1] = fmaf(w.x, s1, acc0[1]); acc1[1] = fmaf(w.y, s1, acc1[1]);
        acc0[2] = fmaf(w.x, s2, acc0[2]); acc1[2] = fmaf(w.y, s2, acc1[2]);
        acc0[3] = fmaf(w.x, s3, acc0[3]); acc1[3] = fmaf(w.y, s3, acc1[3]);
      }
    }
    #pragma unroll
    for (int r = 0; r < 4; r++) {
      size_t ro = (size_t)(row0 + rg * 4 + r) * DIN;
      dt[ro + cd]      = softplusf(acc0[r]);
      dt[ro + cd + 64] = softplusf(acc1[r]);
    }
  }

  // ---- Phase 2b: B/C (32 cols), 2 rows each ----
  {
    int cb2 = t & 31, rg = t >> 5;
    float a0 = 0.f, a1 = 0.f;
    for (int k4 = 0; k4 < 32; k4++) {
      float4 v0 = xt4[(rg * 2 + 0) * 32 + k4];
      float4 v1 = xt4[(rg * 2 + 1) * 32 + k4];
      #pragma unroll
      for (int kk = 0; kk < 4; kk++) {
        float w = Wbc[(k4 * 4 + kk) * 32 + cb2];
        a0 = fmaf(w, getc(v0, kk), a0);
        a1 = fmaf(w, getc(v1, kk), a1);
      }
    }
    size_t r0 = (size_t)row0 + rg * 2;
    float* dst = (cb2 < 16) ? (Bm + r0 * 16 + cb2) : (Cm + r0 * 16 + (cb2 - 16));
    dst[0]  = a0;
    dst[16] = a1;
  }
}

// ---------------- K5a: scan chunk aggregates -------------------------------
__global__ void __launch_bounds__(512) k_scanA(
    const float* __restrict__ dt, const float* __restrict__ Bmat,
    const float* __restrict__ xs, const float* __restrict__ A_log,
    float* __restrict__ Ap, float* __restrict__ Bg) {
  int chunk = blockIdx.x, b = blockIdx.y;
  int t = threadIdx.x;
  int d = t >> 2, q = t & 3;
  const float* al = A_log + d * 16 + q * 4;
  float a0 = -__expf(al[0]), a1 = -__expf(al[1]);
  float a2 = -__expf(al[2]), a3 = -__expf(al[3]);
  size_t base = (size_t)b * LSEQ + (size_t)chunk * CTL;
  const float* dtp = dt + base * DIN + d;
  const float* xsp = xs + base * DIN + d;
  const float4* bp4 = (const float4*)(Bmat + base * 16 + q * 4);
  float h0 = 0.f, h1 = 0.f, h2 = 0.f, h3 = 0.f;
  float p0 = 1.f, p1 = 1.f, p2 = 1.f, p3 = 1.f;
  #pragma unroll 4
  for (int i = 0; i < CTL; i++) {
    float dtv = dtp[(size_t)i * DIN];
    float xv  = xsp[(size_t)i * DIN];
    float4 bA = bp4[i * 4];
    float u = dtv * xv;
    float e;
    e = __expf(dtv * a0); h0 = fmaf(e, h0, u * bA.x); p0 *= e;
    e = __expf(dtv * a1); h1 = fmaf(e, h1, u * bA.y); p1 *= e;
    e = __expf(dtv * a2); h2 = fmaf(e, h2, u * bA.z); p2 *= e;
    e = __expf(dtv * a3); h3 = fmaf(e, h3, u * bA.w); p3 *= e;
  }
  size_t idx = (size_t)chunk * NCHAIN + (size_t)(b * DIN + d) * 16 + q * 4;
  *(float4*)(Ap + idx) = make_float4(p0, p1, p2, p3);
  *(float4*)(Bg + idx) = make_float4(h0, h1, h2, h3);
}

// ---------------- K5b: sequential combine across chunks ----------------
__global__ void k_scanB(const float* __restrict__ Ap, const float* __restrict__ Bg,
                        float* __restrict__ hinit) {
  int chain = blockIdx.x * 64 + threadIdx.x;   // 0..4095
  float h = 0.f;
  for (int c = 0; c < NCH; c++) {
    size_t idx = (size_t)c * NCHAIN + chain;
    hinit[idx] = h;
    h = fmaf(Ap[idx], h, Bg[idx]);
  }
}

// ---------------- K5c: re-scan + gate, then fused out-proj+BN+GELU+res+clip ------
__global__ void __launch_bounds__(512) k_scanC(
    const float* __restrict__ dt, const float* __restrict__ Bmat,
    const float* __restrict__ Cmat, const float* __restrict__ xs,
    const float* __restrict__ z, const float* __restrict__ A_log,
    const float* __restrict__ Dp, const float* __restrict__ hinit,
    const float* __restrict__ Mtp, const float* __restrict__ bp,
    const float* __restrict__ bn_g, const float* __restrict__ bn_bt,
    const float* __restrict__ bn_m, const float* __restrict__ bn_v,
    const float* __restrict__ res, float* __restrict__ out) {
  int chunk = blockIdx.x, b = blockIdx.y;
  int t = threadIdx.x;
  __shared__ float ytile[CTL * DIN];         // 24.6 KB
  __shared__ float trans[64 * 52];           // 13.3 KB
  {
    int d = t >> 2, q = t & 3;
    const float* al = A_log + d * 16 + q * 4;
    float a0 = -__expf(al[0]), a1 = -__expf(al[1]);
    float a2 = -__expf(al[2]), a3 = -__expf(al[3]);
    float dp = Dp[d];
    size_t base = (size_t)b * LSEQ + (size_t)chunk * CTL;
    const float* dtp = dt + base * DIN + d;
    const float* xsp = xs + base * DIN + d;
    const float* zp  = z  + base * DIN + d;
    const float4* bp4 = (const float4*)(Bmat + base * 16 + q * 4);
    const float4* cp4 = (const float4*)(Cmat + base * 16 + q * 4);
    size_t idx = (size_t)chunk * NCHAIN + (size_t)(b * DIN + d) * 16 + q * 4;
    float4 hv = *(const float4*)(hinit + idx);
    float h0 = hv.x, h1 = hv.y, h2 = hv.z, h3 = hv.w;
    #pragma unroll 2
    for (int i = 0; i < CTL; i++) {
      float dtv = dtp[(size_t)i * DIN];
      float xv  = xsp[(size_t)i * DIN];
      float4 bA = bp4[i * 4];
      float4 cA = cp4[i * 4];
      float u = dtv * xv;
      float e, p;
      e = __expf(dtv * a0); h0 = fmaf(e, h0, u * bA.x); p = h0 * cA.x;
      e = __expf(dtv * a1); h1 = fmaf(e, h1, u * bA.y); p = fmaf(h1, cA.y, p);
      e = __expf(dtv * a2); h2 = fmaf(e, h2, u * bA.z); p = fmaf(h2, cA.z, p);
      e = __expf(dtv * a3); h3 = fmaf(e, h3, u * bA.w); p = fmaf(h3, cA.w, p);
      p += __shfl_xor(p, 1);
      p += __shfl_xor(p, 2);
      if (q == 0) {
        float zv = zp[(size_t)i * DIN];
        ytile[i * DIN + d] = (p + xv * dp) * siluf(zv);
      }
    }
  }
  __syncthreads();

  // GEMM 48x128 @ Mtp -> 48x64, BN + GELU
  {
    int op = t & 31, rg = t >> 5;             // rg 0..15, 3 rows each
    float acc0[3], acc1[3];
    float b0 = bp[op], b1 = bp[op + 32];
    #pragma unroll
    for (int r = 0; r < 3; r++) { acc0[r] = b0; acc1[r] = b1; }
    const float4* yt4 = (const float4*)ytile;
    const float2* M2  = (const float2*)Mtp;
    for (int k4 = 0; k4 < 32; k4++) {
      float4 v0 = yt4[(rg * 3 + 0) * 32 + k4];
      float4 v1 = yt4[(rg * 3 + 1) * 32 + k4];
      float4 v2 = yt4[(rg * 3 + 2) * 32 + k4];
      #pragma unroll
      for (int kk = 0; kk < 4; kk++) {
        float2 w = M2[(size_t)(k4 * 4 + kk) * 32 + op];
        float s0 = getc(v0, kk), s1 = getc(v1, kk), s2 = getc(v2, kk);
        acc0[0] = fmaf(w.x, s0, acc0[0]); acc1[0] = fmaf(w.y, s0, acc1[0]);
        acc0[1] = fmaf(w.x, s1, acc0[1]); acc1[1] = fmaf(w.y, s1, acc1[1]);
        acc0[2] = fmaf(w.x, s2, acc0[2]); acc1[2] = fmaf(w.y, s2, acc1[2]);
      }
    }
    float g0 = bn_g[op], bt0 = bn_bt[op], mu0 = bn_m[op];
    float iv0 = rsqrtf(bn_v[op] + 1e-5f);
    float g1 = bn_g[op + 32], bt1 = bn_bt[op + 32], mu1 = bn_m[op + 32];
    float iv1 = rsqrtf(bn_v[op + 32] + 1e-5f);
    __syncthreads();
    #pragma unroll
    for (int r = 0; r < 3; r++) {
      int row = rg * 3 + r;
      float a = (acc0[r] - mu0) * iv0 * g0 + bt0;
      a = 0.5f * a * (1.f + erff(a * 0.70710678118654752f));
      trans[op * 52 + row] = a;
      float a2 = (acc1[r] - mu1) * iv1 * g1 + bt1;
      a2 = 0.5f * a2 * (1.f + erff(a2 * 0.70710678118654752f));
      trans[(op + 32) * 52 + row] = a2;
    }
  }
  __syncthreads();

  // coalesced store: out[(b*64+c)*LSEQ + chunk*48 + l] with residual+clip
  int l0c = chunk * CTL;
  for (int task = t; task < 768; task += 512) {   // 64 c * 12 f4
    int c = task / 12, f = task - c * 12;
    float4 vv = *(const float4*)(trans + c * 52 + f * 4);
    size_t gi = ((size_t)(b * DIMC + c)) * LSEQ + l0c + f * 4;
    const float4 rv = *(const float4*)(res + gi);
    float4 o;
    o.x = clip10(rv.x + vv.x);
    o.y = clip10(rv.y + vv.y);
    o.z = clip10(rv.z + vv.z);
    o.w = clip10(rv.w + vv.w);
    *(float4*)(out + gi) = o;
  }
}

extern "C" void kernel_launch(void* const* d_in, const int* in_sizes, int n_in,
                              void* d_out, int out_size, void* d_ws, size_t ws_size,
                              hipStream_t stream) {
  const float* x       = (const float*)d_in[0];
  const float* gn_g    = (const float*)d_in[1];
  const float* gn_b    = (const float*)d_in[2];
  const float* W_in    = (const float*)d_in[3];
  const float* b_in    = (const float*)d_in[4];
  const float* conv_w  = (const float*)d_in[5];
  const float* conv_b  = (const float*)d_in[6];
  const float* W_xproj = (const float*)d_in[7];
  const float* W_dt    = (const float*)d_in[8];
  const float* b_dt    = (const float*)d_in[9];
  const float* A_log   = (const float*)d_in[10];
  const float* Dp      = (const float*)d_in[11];
  const float* W_out   = (const float*)d_in[12];
  const float* b_out   = (const float*)d_in[13];
  const float* proj_w  = (const float*)d_in[14];
  const float* proj_b  = (const float*)d_in[15];
  const float* bn_g    = (const float*)d_in[16];
  const float* bn_bt   = (const float*)d_in[17];
  const float* bn_m    = (const float*)d_in[18];
  const float* bn_v    = (const float*)d_in[19];

  float* ws = (float*)d_ws;
  float* sums = ws;                               // 64
  float* seq  = ws + 64;                          // 1179648 (B,L,C); dead after k_mid
  float* res  = seq + 1179648;                    // 1179648 (B,C,L)
  float* zbuf = res + 1179648;                    // 2359296
  float* xsb  = zbuf + 2359296;                   // 2359296
  float* dtb  = xsb + 2359296;                    // 2359296
  float* Bmb  = dtb + 2359296;                    // 294912
  float* Cmb  = Bmb + 294912;                     // 294912
  float* Wtp  = Cmb + 294912;                     // 16384
  float* Mtp  = Wtp + 16384;                      // 8192
  float* bp   = Mtp + 8192;                       // 64
  float* Wbtd2= bp + 64;                          // 16384
  float* Wbc  = Wbtd2 + 16384;                    // 4096
  float* Bgb  = Wbc + 4096;                       // 786432 (NCH*NCHAIN)
  float* hib  = Bgb + 786432;                     // 786432
  float* Apb  = seq;                              // 786432, reuses dead seq

  hipMemsetAsync(sums, 0, 64 * sizeof(float), stream);

  k_init<<<dim3(433, 2), 256, 0, stream>>>(x, sums, W_in, proj_w, W_out, b_out, proj_b,
                                           W_xproj, W_dt, Wtp, Mtp, bp, Wbtd2, Wbc);
  k_norm<<<dim3(144, 2), 256, 0, stream>>>(x, gn_g, gn_b, sums, seq, res);
  k_mid<<<1152, 256, 0, stream>>>(seq, Wtp, b_in, conv_w, conv_b, Wbtd2, Wbc, b_dt,
                                  xsb, zbuf, dtb, Bmb, Cmb);
  k_scanA<<<dim3(NCH, 2), 512, 0, stream>>>(dtb, Bmb, xsb, A_log, Apb, Bgb);
  k_scanB<<<64, 64, 0, stream>>>(Apb, Bgb, hib);
  k_scanC<<<dim3(NCH, 2), 512, 0, stream>>>(dtb, Bmb, Cmb, xsb, zbuf, A_log, Dp, hib,
                                            Mtp, bp, bn_g, bn_bt, bn_m, bn_v, res,
                                            (float*)d_out);
}